// Round 13
// baseline (320.829 us; speedup 1.0000x reference)
//
#include <hip/hip_runtime.h>

// UserGraphNet: B=64 graphs, n=714 nodes, E=16384 edges (+n self loops), C=128.
// Round 12: fuse each aggregate with the FOLLOWING GEMM (agg -> LDS A-tile -> MFMA
// in one kernel; asrc/adst for the next layer computed in the agg epilogue).
// 13 kernels -> 7 in the GAT chain; bufA global round trips eliminated.
// Agg = 2 nodes/wave register softmax (round 11). f16 features, 2-term MFMA,
// fused CSR build, table-projection embed, XCD swizzle.

#define BB 64
#define NN 714
#define EE 16384
#define ET (EE + NN)          // 17098 edges incl self loops
#define NBt (BB * NN)         // 45696 total nodes
#define CC 128
#define RP (NN + 1)           // rowptr entries per graph
#define DFAST 64              // max degree on the half-wave fast path (deg~24)
#define KSP 28                // total padded k-steps across 4 table projections
#define PROJ_ROWS 19021       // 5099 + 400 + 7128 + 6394

typedef _Float16 f16;
typedef __attribute__((ext_vector_type(8))) _Float16 f16x8;
typedef __attribute__((ext_vector_type(4))) _Float16 f16x4;
typedef __attribute__((ext_vector_type(4))) float f32x4;

__device__ __forceinline__ float lrelu01(float x) { return x > 0.f ? x : 0.01f * x; }
__device__ __forceinline__ float lrelu2(float x)  { return x > 0.f ? x : 0.2f  * x; }

__device__ __forceinline__ float wsum(float x) {
#pragma unroll
    for (int o = 32; o > 0; o >>= 1) x += __shfl_xor(x, o);
    return x;
}
__device__ __forceinline__ float hsum(float x) {
#pragma unroll
    for (int o = 16; o > 0; o >>= 1) x += __shfl_xor(x, o);
    return x;
}
__device__ __forceinline__ float hmax(float x) {
#pragma unroll
    for (int o = 16; o > 0; o >>= 1) x = fmaxf(x, __shfl_xor(x, o));
    return x;
}

// Bijective XCD swizzle (m204)
__device__ __forceinline__ int xcd_swz(int bid, int nwg) {
    int q = nwg >> 3, r = nwg & 7;
    int x = bid & 7, l = bid >> 3;
    int base = (x < r) ? x * (q + 1) : r * (q + 1) + (x - r) * q;
    return base + l;
}

// ---- fused CSR build: one block per graph; LDS histogram + scan + scatter ----
__global__ __launch_bounds__(1024) void k_build(
    const int* __restrict__ edges, int* __restrict__ rowptr,
    int* __restrict__ csr_row, float* __restrict__ dinv) {
    __shared__ int degs[NN];
    __shared__ int scan[1024];
    __shared__ int curs[NN];
    int b = blockIdx.x, t = threadIdx.x;
    if (t < NN) degs[t] = 0;
    __syncthreads();
    int rr[17], cc[17];
#pragma unroll
    for (int q = 0; q < 17; ++q) {
        int e = q * 1024 + t;
        int r = -1, c = -1;
        if (e < ET) {
            if (e < EE) { r = edges[b * 2 * EE + e]; c = edges[b * 2 * EE + EE + e]; }
            else        { r = c = e - EE; }
            atomicAdd(&degs[c], 1);
        }
        rr[q] = r; cc[q] = c;
    }
    __syncthreads();
    int cnt = (t < NN) ? degs[t] : 0;
    scan[t] = cnt;
    __syncthreads();
    for (int off = 1; off < 1024; off <<= 1) {
        int val = (t >= off) ? scan[t - off] : 0;
        __syncthreads();
        scan[t] += val;
        __syncthreads();
    }
    if (t < NN) {
        rowptr[b * RP + t + 1] = scan[t];
        curs[t] = scan[t] - cnt;                       // exclusive prefix
        dinv[b * NN + t] = cnt > 0 ? rsqrtf((float)cnt) : 0.f;
    }
    if (t == 0) rowptr[b * RP] = 0;
    __syncthreads();
#pragma unroll
    for (int q = 0; q < 17; ++q) {
        if (cc[q] >= 0) {
            int slot = atomicAdd(&curs[cc[q]], 1);     // LDS atomic
            csr_row[b * ET + slot] = rr[q];
        }
    }
}

// ---- merged prep: pack W_in table-slices, pack gat_W, compute w_s/w_d ----
#define NSEG (KSP * 8 * 64)
#define NGAT (3 * 4 * 8 * 64)
__global__ void k_prep(const float* __restrict__ W, const float* __restrict__ gat_W,
                       const float* __restrict__ a_s, const float* __restrict__ a_d,
                       f16* __restrict__ BWh, f16* __restrict__ BWl,
                       f16* __restrict__ BGh, f16* __restrict__ BGl,
                       float* __restrict__ wsv, float* __restrict__ wdv) {
    int idx = blockIdx.x * 256 + threadIdx.x;
    if (idx < NSEG) {
        int lane = idx & 63, tc = idx >> 6;
        int ct = tc & 7, ks = tc >> 3;
        int t  = ks < 10 ? 0 : ks < 14 ? 1 : ks < 21 ? 2 : 3;
        int k0 = t == 0 ? 0 : t == 1 ? 10 : t == 2 ? 14 : 21;
        const int Ktab[4] = {300, 100, 200, 200};
        const int Koff[4] = {0, 300, 400, 600};
        int ksl = ks - k0;
        f16x8 ph, pl;
#pragma unroll
        for (int j = 0; j < 8; ++j) {
            int k = ksl * 32 + (lane >> 4) * 8 + j;
            int c = ct * 16 + (lane & 15);
            float v = (k < Ktab[t]) ? W[(size_t)(Koff[t] + k) * CC + c] : 0.f;
            f16 hi = (f16)v;
            ph[j] = hi; pl[j] = (f16)(v - (float)hi);
        }
        *(f16x8*)(BWh + (size_t)idx * 8) = ph;
        *(f16x8*)(BWl + (size_t)idx * 8) = pl;
    } else if (idx < NSEG + NGAT) {
        int i2 = idx - NSEG;
        int lane = i2 & 63, tc = i2 >> 6;
        int ct = tc & 7; tc >>= 3;
        int ks = tc & 3, li = tc >> 2;
        const float* Wl = gat_W + (size_t)li * CC * CC;
        f16x8 ph, pl;
#pragma unroll
        for (int j = 0; j < 8; ++j) {
            int k = ks * 32 + (lane >> 4) * 8 + j;
            int c = ct * 16 + (lane & 15);
            float v = Wl[k * CC + c];
            f16 hi = (f16)v;
            ph[j] = hi; pl[j] = (f16)(v - (float)hi);
        }
        *(f16x8*)(BGh + (size_t)i2 * 8) = ph;
        *(f16x8*)(BGl + (size_t)i2 * 8) = pl;
    } else if (idx < NSEG + NGAT + 3 * CC) {
        int i2 = idx - NSEG - NGAT;
        int i = i2 >> 7, k = i2 & 127;
        const float* Wl = gat_W + (size_t)i * CC * CC;
        float s = 0.f, d = 0.f;
#pragma unroll 4
        for (int c = 0; c < CC; ++c) {
            float w = Wl[k * CC + c];
            s = fmaf(w, a_s[i * CC + c], s);
            d = fmaf(w, a_d[i * CC + c], d);
        }
        wsv[i * CC + k] = s; wdv[i * CC + k] = d;
    }
}

// ---- table-projection GEMM: P[t] = table[t] @ W_in[Koff:Koff+K]  (f32 out) ----
__global__ __launch_bounds__(256) void k_proj(
    const float* __restrict__ poi, const float* __restrict__ cat,
    const float* __restrict__ lat, const float* __restrict__ lon,
    const f16* __restrict__ Bh, const f16* __restrict__ Bl,
    float* __restrict__ P) {
    int bid = blockIdx.x;
    int t, r0;
    if (bid < 160)      { t = 0; r0 = bid * 32; }
    else if (bid < 173) { t = 1; r0 = (bid - 160) * 32; }
    else if (bid < 396) { t = 2; r0 = (bid - 173) * 32; }
    else                { t = 3; r0 = (bid - 396) * 32; }
    const int Ktab[4] = {300, 100, 200, 200};
    const int Rtab[4] = {5099, 400, 7128, 6394};
    const int Rofs[4] = {0, 5099, 5499, 12627};
    const int Kst[4]  = {10, 4, 7, 7};
    const int Bks0[4] = {0, 10, 14, 21};
    const float* tab = t == 0 ? poi : t == 1 ? cat : t == 2 ? lat : lon;
    int K = Ktab[t], R = Rtab[t], nks = Kst[t], bks = Bks0[t];
    int lane = threadIdx.x & 63, w = threadIdx.x >> 6;
    int ct0 = w * 2;
    f32x4 acc[2][2];
#pragma unroll
    for (int rt = 0; rt < 2; ++rt)
#pragma unroll
        for (int c = 0; c < 2; ++c) acc[rt][c] = (f32x4){0.f, 0.f, 0.f, 0.f};

    for (int ks = 0; ks < nks; ++ks) {
        int kbase = ks * 32 + (lane >> 4) * 8;
        f16x8 ah[2], al[2];
#pragma unroll
        for (int rt = 0; rt < 2; ++rt) {
            int row = r0 + rt * 16 + (lane & 15);
            int rowc = row < R ? row : R - 1;
            const float* rp = tab + (size_t)rowc * K;
            float v[8];
            if (kbase + 8 <= K) {
                float4 x0 = ((const float4*)(rp + kbase))[0];
                float4 x1 = ((const float4*)(rp + kbase))[1];
                v[0] = x0.x; v[1] = x0.y; v[2] = x0.z; v[3] = x0.w;
                v[4] = x1.x; v[5] = x1.y; v[6] = x1.z; v[7] = x1.w;
            } else if (kbase >= K) {
#pragma unroll
                for (int m = 0; m < 8; ++m) v[m] = 0.f;
            } else {
#pragma unroll
                for (int m = 0; m < 8; ++m) v[m] = (kbase + m < K) ? rp[kbase + m] : 0.f;
            }
#pragma unroll
            for (int j = 0; j < 8; ++j) {
                f16 hi = (f16)v[j];
                ah[rt][j] = hi; al[rt][j] = (f16)(v[j] - (float)hi);
            }
        }
#pragma unroll
        for (int cti = 0; cti < 2; ++cti) {
            int ct = ct0 + cti;
            f16x8 bh = *(const f16x8*)(Bh + ((size_t)((bks + ks) * 8 + ct) * 64 + lane) * 8);
            f16x8 bl = *(const f16x8*)(Bl + ((size_t)((bks + ks) * 8 + ct) * 64 + lane) * 8);
#pragma unroll
            for (int rt = 0; rt < 2; ++rt) {
                acc[rt][cti] = __builtin_amdgcn_mfma_f32_16x16x32_f16(ah[rt], bh, acc[rt][cti], 0, 0, 0);
                acc[rt][cti] = __builtin_amdgcn_mfma_f32_16x16x32_f16(al[rt], bh, acc[rt][cti], 0, 0, 0);
                acc[rt][cti] = __builtin_amdgcn_mfma_f32_16x16x32_f16(ah[rt], bl, acc[rt][cti], 0, 0, 0);
            }
        }
    }
#pragma unroll
    for (int rt = 0; rt < 2; ++rt)
#pragma unroll
        for (int cti = 0; cti < 2; ++cti)
#pragma unroll
            for (int i = 0; i < 4; ++i) {
                int row = r0 + rt * 16 + (lane >> 4) * 4 + i;
                if (row < R) {
                    int col = (ct0 + cti) * 16 + (lane & 15);
                    P[(size_t)(Rofs[t] + row) * CC + col] = acc[rt][cti][i];
                }
            }
}

// ---- per-node assembly: bufB[g] = P_poi[f0] + P_cat[f1] + P_lat[f3] + P_lon[f4] ----
__global__ __launch_bounds__(256) void k_assemble(
    const int* __restrict__ feature, const float* __restrict__ P,
    f16* __restrict__ out) {
    int tid = xcd_swz(blockIdx.x, gridDim.x) * 256 + threadIdx.x;
    int g = tid >> 4, c8 = (tid & 15) * 8;
    const int* f = feature + (size_t)g * 5;
    const float4* p0 = (const float4*)(P + (size_t)f[0] * CC + c8);
    const float4* p1 = (const float4*)(P + (size_t)(5099 + f[1]) * CC + c8);
    const float4* p2 = (const float4*)(P + (size_t)(5499 + f[3]) * CC + c8);
    const float4* p3 = (const float4*)(P + (size_t)(12627 + f[4]) * CC + c8);
    float4 a0 = p0[0], a1 = p0[1];
    float4 b0 = p1[0], b1 = p1[1];
    float4 c0 = p2[0], c1 = p2[1];
    float4 d0 = p3[0], d1 = p3[1];
    f16x8 r;
    r[0] = (f16)(a0.x + b0.x + c0.x + d0.x);
    r[1] = (f16)(a0.y + b0.y + c0.y + d0.y);
    r[2] = (f16)(a0.z + b0.z + c0.z + d0.z);
    r[3] = (f16)(a0.w + b0.w + c0.w + d0.w);
    r[4] = (f16)(a1.x + b1.x + c1.x + d1.x);
    r[5] = (f16)(a1.y + b1.y + c1.y + d1.y);
    r[6] = (f16)(a1.z + b1.z + c1.z + d1.z);
    r[7] = (f16)(a1.w + b1.w + c1.w + d1.w);
    *(f16x8*)(out + (size_t)g * CC + c8) = r;
}

// ---- FUSED aggregate + GEMM: one block = 32 nodes ----
// Phase A: agg (2 nodes/wave, register softmax) -> swizzled LDS A-tile + next
// asrc/adst. Phase B: 32-row MFMA GEMM (2-term split-f16 B) -> Hp (f16).
// MODE 2: GCN (aux=dinv), h=lrelu01(t). MODE 0: GAT, h=lrelu01(t)+t.
// MODE 1: GAT, h=lrelu01(t).
template <int MODE>
__global__ __launch_bounds__(256) void k_agg_gemm(
    const f16* __restrict__ Hin, const float* __restrict__ aux,
    const float* __restrict__ adst, const int* __restrict__ rowptr,
    const int* __restrict__ csr_row, const float* __restrict__ bias,
    const f16* __restrict__ Bh, const f16* __restrict__ Bl,
    const float* __restrict__ wsv, const float* __restrict__ wdv,
    f16* __restrict__ Hp, float* __restrict__ asrc_o, float* __restrict__ adst_o) {
    __shared__ __align__(16) f16 Ah[32 * 128];
    __shared__ float2 pr[4][2][DFAST];
    int t = threadIdx.x;
    int wid = t >> 6, lane = t & 63;
    int half = lane >> 5, hl = lane & 31;
    int g0 = xcd_swz(blockIdx.x, gridDim.x) * 32;

    // ================= Phase A: aggregate 32 nodes =================
    for (int it = 0; it < 4; ++it) {
        int ln = wid * 2 + half + it * 8;          // local node 0..31
        int g = g0 + ln;
        int b = g / NN, v = g - b * NN;
        int bN = b * NN, bE = b * ET;
        int s0 = rowptr[b * RP + v], s1 = rowptr[b * RP + v + 1];
        int deg = s1 - s0;

        if (deg <= DFAST) {
            int degp = (deg + 7) & ~7;
            float inv = 1.f;
            int r0i = 0, r1i = 0;
            float w0v, w1v;
            if (MODE == 2) {
                float dv = aux[g];
                w0v = w1v = 0.f;
                if (hl < deg)      { r0i = csr_row[bE + s0 + hl];      w0v = aux[bN + r0i] * dv; }
                if (hl + 32 < deg) { r1i = csr_row[bE + s0 + hl + 32]; w1v = aux[bN + r1i] * dv; }
            } else {
                float adv = adst[g];
                float e0 = -3.0e38f, e1 = -3.0e38f;
                if (hl < deg)      { r0i = csr_row[bE + s0 + hl];      e0 = lrelu2(aux[bN + r0i] + adv); }
                if (hl + 32 < deg) { r1i = csr_row[bE + s0 + hl + 32]; e1 = lrelu2(aux[bN + r1i] + adv); }
                float m = hmax(fmaxf(e0, e1));
                w0v = __expf(e0 - m);
                w1v = __expf(e1 - m);
                float ss = hsum(w0v + w1v);
                inv = 1.f / (ss + 1e-16f);
            }
            if (hl < degp)      pr[wid][half][hl]      = make_float2(w0v, __int_as_float(r0i));
            if (hl + 32 < degp) pr[wid][half][hl + 32] = make_float2(w1v, __int_as_float(r1i));
            // same-wave DS ordering: phase-2 reads see these writes
            int eh = hl >> 4, ql = hl & 15;
            const f16* Hb = Hin + (size_t)bN * CC;
            float acc0[8], acc1[8], acc2[8], acc3[8];
#pragma unroll
            for (int j = 0; j < 8; ++j) { acc0[j] = 0.f; acc1[j] = 0.f; acc2[j] = 0.f; acc3[j] = 0.f; }
            for (int jj = 0; jj < degp; jj += 8) {
                float2 p0 = pr[wid][half][jj + eh];
                float2 p1 = pr[wid][half][jj + 2 + eh];
                float2 p2 = pr[wid][half][jj + 4 + eh];
                float2 p3 = pr[wid][half][jj + 6 + eh];
                f16x8 h0 = *(const f16x8*)(Hb + (size_t)__float_as_int(p0.y) * CC + ql * 8);
                f16x8 h1 = *(const f16x8*)(Hb + (size_t)__float_as_int(p1.y) * CC + ql * 8);
                f16x8 h2 = *(const f16x8*)(Hb + (size_t)__float_as_int(p2.y) * CC + ql * 8);
                f16x8 h3 = *(const f16x8*)(Hb + (size_t)__float_as_int(p3.y) * CC + ql * 8);
#pragma unroll
                for (int j = 0; j < 8; ++j) {
                    acc0[j] = fmaf((float)h0[j], p0.x, acc0[j]);
                    acc1[j] = fmaf((float)h1[j], p1.x, acc1[j]);
                    acc2[j] = fmaf((float)h2[j], p2.x, acc2[j]);
                    acc3[j] = fmaf((float)h3[j], p3.x, acc3[j]);
                }
            }
            float ov[8];
            float sc = (MODE == 2) ? 1.f : inv;
            float4 bb0 = ((const float4*)bias)[ql * 2];
            float4 bb1 = ((const float4*)bias)[ql * 2 + 1];
#pragma unroll
            for (int j = 0; j < 8; ++j) {
                float x = acc0[j] + acc1[j] + acc2[j] + acc3[j];
                x += __shfl_xor(x, 16);            // both eh groups now hold sum
                float bv = (j < 4) ? ((const float*)&bb0)[j] : ((const float*)&bb1)[j - 4];
                float tv = x * sc + bv;
                float l = lrelu01(tv);
                ov[j] = (MODE == 0) ? l + tv : l;
            }
            // next-layer asrc/adst: dot(ov, wsv/wdv) over this lane's 8 cols
            float ps = 0.f, pd = 0.f;
#pragma unroll
            for (int j = 0; j < 8; ++j) {
                ps = fmaf(ov[j], wsv[ql * 8 + j], ps);
                pd = fmaf(ov[j], wdv[ql * 8 + j], pd);
            }
#pragma unroll
            for (int o = 8; o > 0; o >>= 1) {
                ps += __shfl_xor(ps, o);
                pd += __shfl_xor(pd, o);
            }
            if (hl == 0) { asrc_o[g] = ps; adst_o[g] = pd; }
            if (eh == 0) {
                f16x8 r;
#pragma unroll
                for (int j = 0; j < 8; ++j) r[j] = (f16)ov[j];
                *(f16x8*)&Ah[ln * 128 + ((ql ^ (ln & 7)) << 3)] = r;
            }
        } else {
            // fallback deg > DFAST (half-wave, 4 cols/lane); ~never taken
            float wsc0 = 0.f, m = 0.f, inv = 1.f, adv = 0.f;
            if (MODE != 2) {
                adv = adst[g];
                m = -3.0e38f;
                for (int j = s0 + hl; j < s1; j += 32)
                    m = fmaxf(m, lrelu2(aux[bN + csr_row[bE + j]] + adv));
                m = hmax(m);
                float ssum = 0.f;
                for (int j = s0 + hl; j < s1; j += 32)
                    ssum += __expf(lrelu2(aux[bN + csr_row[bE + j]] + adv) - m);
                ssum = hsum(ssum);
                inv = 1.f / (ssum + 1e-16f);
            } else {
                wsc0 = aux[g];
            }
            float x0 = 0.f, x1 = 0.f, x2 = 0.f, x3 = 0.f;
            for (int j = s0; j < s1; ++j) {
                int r = csr_row[bE + j];
                float wj = (MODE == 2) ? aux[bN + r]
                                       : __expf(lrelu2(aux[bN + r] + adv) - m) * inv;
                f16x4 h = *(const f16x4*)(Hin + (size_t)(bN + r) * CC + hl * 4);
                x0 = fmaf(wj, (float)h[0], x0);
                x1 = fmaf(wj, (float)h[1], x1);
                x2 = fmaf(wj, (float)h[2], x2);
                x3 = fmaf(wj, (float)h[3], x3);
            }
            if (MODE == 2) { x0 *= wsc0; x1 *= wsc0; x2 *= wsc0; x3 *= wsc0; }
            float4 bb = ((const float4*)bias)[hl];
            float t0 = x0 + bb.x, t1 = x1 + bb.y, t2 = x2 + bb.z, t3 = x3 + bb.w;
            float o0 = (MODE == 0) ? lrelu01(t0) + t0 : lrelu01(t0);
            float o1 = (MODE == 0) ? lrelu01(t1) + t1 : lrelu01(t1);
            float o2 = (MODE == 0) ? lrelu01(t2) + t2 : lrelu01(t2);
            float o3 = (MODE == 0) ? lrelu01(t3) + t3 : lrelu01(t3);
            float4 wsv4 = ((const float4*)wsv)[hl];
            float4 wdv4 = ((const float4*)wdv)[hl];
            float ps = o0 * wsv4.x + o1 * wsv4.y + o2 * wsv4.z + o3 * wsv4.w;
            float pd = o0 * wdv4.x + o1 * wdv4.y + o2 * wdv4.z + o3 * wdv4.w;
            ps = hsum(ps); pd = hsum(pd);
            if (hl == 0) { asrc_o[g] = ps; adst_o[g] = pd; }
            int kg = hl >> 1;
            f16x4 r;
            r[0] = (f16)o0; r[1] = (f16)o1; r[2] = (f16)o2; r[3] = (f16)o3;
            *(f16x4*)&Ah[ln * 128 + ((kg ^ (ln & 7)) << 3) + (hl & 1) * 4] = r;
        }
    }
    __syncthreads();

    // ================= Phase B: 32-row MFMA GEMM =================
    f32x4 acc[2][2];
#pragma unroll
    for (int rt = 0; rt < 2; ++rt)
#pragma unroll
        for (int c = 0; c < 2; ++c) acc[rt][c] = (f32x4){0.f, 0.f, 0.f, 0.f};
    int ct0 = wid * 2;
#pragma unroll
    for (int ks = 0; ks < 4; ++ks) {
        f16x8 ahf[2];
#pragma unroll
        for (int rt = 0; rt < 2; ++rt) {
            int r = rt * 16 + (lane & 15);
            int kg = (lane >> 4) + ks * 4;
            int ad = r * 128 + ((kg ^ (r & 7)) << 3);
            ahf[rt] = *(const f16x8*)&Ah[ad];
        }
#pragma unroll
        for (int cti = 0; cti < 2; ++cti) {
            int ct = ct0 + cti;
            f16x8 bh = *(const f16x8*)(Bh + ((size_t)(ks * 8 + ct) * 64 + lane) * 8);
            f16x8 bl = *(const f16x8*)(Bl + ((size_t)(ks * 8 + ct) * 64 + lane) * 8);
#pragma unroll
            for (int rt = 0; rt < 2; ++rt) {
                acc[rt][cti] = __builtin_amdgcn_mfma_f32_16x16x32_f16(ahf[rt], bh, acc[rt][cti], 0, 0, 0);
                acc[rt][cti] = __builtin_amdgcn_mfma_f32_16x16x32_f16(ahf[rt], bl, acc[rt][cti], 0, 0, 0);
            }
        }
    }
#pragma unroll
    for (int rt = 0; rt < 2; ++rt)
#pragma unroll
        for (int cti = 0; cti < 2; ++cti)
#pragma unroll
            for (int i = 0; i < 4; ++i) {
                int row = g0 + rt * 16 + (lane >> 4) * 4 + i;
                int col = (ct0 + cti) * 16 + (lane & 15);
                Hp[(size_t)row * CC + col] = (f16)acc[rt][cti][i];
            }
}

// ---- final standalone aggregate (MODE 3): softmax agg + fused W_out dot ----
__global__ __launch_bounds__(256) void k_agg_last(
    const f16* __restrict__ Hp, const float* __restrict__ asrc,
    const float* __restrict__ adst, const int* __restrict__ rowptr,
    const int* __restrict__ csr_row, const float* __restrict__ bias,
    const float* __restrict__ Wout, float* __restrict__ pscal) {
    __shared__ float2 pr[4][2][DFAST];
    int wid = threadIdx.x >> 6, lane = threadIdx.x & 63;
    int half = lane >> 5, hl = lane & 31;
    int g = xcd_swz(blockIdx.x, gridDim.x) * 8 + wid * 2 + half;
    int b = g / NN, v = g - b * NN;
    int bN = b * NN, bE = b * ET;
    int s0 = rowptr[b * RP + v], s1 = rowptr[b * RP + v + 1];
    int deg = s1 - s0;

    if (deg <= DFAST) {
        int degp = (deg + 7) & ~7;
        float adv = adst[g];
        float e0 = -3.0e38f, e1 = -3.0e38f;
        int r0i = 0, r1i = 0;
        if (hl < deg)      { r0i = csr_row[bE + s0 + hl];      e0 = lrelu2(asrc[bN + r0i] + adv); }
        if (hl + 32 < deg) { r1i = csr_row[bE + s0 + hl + 32]; e1 = lrelu2(asrc[bN + r1i] + adv); }
        float m = hmax(fmaxf(e0, e1));
        float w0v = __expf(e0 - m), w1v = __expf(e1 - m);
        float ss = hsum(w0v + w1v);
        float inv = 1.f / (ss + 1e-16f);
        if (hl < degp)      pr[wid][half][hl]      = make_float2(w0v, __int_as_float(r0i));
        if (hl + 32 < degp) pr[wid][half][hl + 32] = make_float2(w1v, __int_as_float(r1i));
        int eh = hl >> 4, ql = hl & 15;
        const f16* Hb = Hp + (size_t)bN * CC;
        float acc0[8], acc1[8], acc2[8], acc3[8];
#pragma unroll
        for (int j = 0; j < 8; ++j) { acc0[j] = 0.f; acc1[j] = 0.f; acc2[j] = 0.f; acc3[j] = 0.f; }
        for (int jj = 0; jj < degp; jj += 8) {
            float2 p0 = pr[wid][half][jj + eh];
            float2 p1 = pr[wid][half][jj + 2 + eh];
            float2 p2 = pr[wid][half][jj + 4 + eh];
            float2 p3 = pr[wid][half][jj + 6 + eh];
            f16x8 h0 = *(const f16x8*)(Hb + (size_t)__float_as_int(p0.y) * CC + ql * 8);
            f16x8 h1 = *(const f16x8*)(Hb + (size_t)__float_as_int(p1.y) * CC + ql * 8);
            f16x8 h2 = *(const f16x8*)(Hb + (size_t)__float_as_int(p2.y) * CC + ql * 8);
            f16x8 h3 = *(const f16x8*)(Hb + (size_t)__float_as_int(p3.y) * CC + ql * 8);
#pragma unroll
            for (int j = 0; j < 8; ++j) {
                acc0[j] = fmaf((float)h0[j], p0.x, acc0[j]);
                acc1[j] = fmaf((float)h1[j], p1.x, acc1[j]);
                acc2[j] = fmaf((float)h2[j], p2.x, acc2[j]);
                acc3[j] = fmaf((float)h3[j], p3.x, acc3[j]);
            }
        }
        float4 bb0 = ((const float4*)bias)[ql * 2];
        float4 bb1 = ((const float4*)bias)[ql * 2 + 1];
        float4 w0 = ((const float4*)Wout)[ql * 2];
        float4 w1 = ((const float4*)Wout)[ql * 2 + 1];
        float p = 0.f;
#pragma unroll
        for (int j = 0; j < 8; ++j) {
            float x = acc0[j] + acc1[j] + acc2[j] + acc3[j];
            x += __shfl_xor(x, 16);
            float bv = (j < 4) ? ((const float*)&bb0)[j] : ((const float*)&bb1)[j - 4];
            float wv = (j < 4) ? ((const float*)&w0)[j] : ((const float*)&w1)[j - 4];
            float tv = x * inv + bv;
            p = fmaf(lrelu01(tv), wv, p);
        }
#pragma unroll
        for (int o = 8; o > 0; o >>= 1) p += __shfl_xor(p, o);
        if (hl == 0) pscal[g] = p;
        return;
    }
    // fallback deg > DFAST
    {
        float adv = adst[g];
        float m = -3.0e38f;
        for (int j = s0 + hl; j < s1; j += 32)
            m = fmaxf(m, lrelu2(asrc[bN + csr_row[bE + j]] + adv));
        m = hmax(m);
        float ssum = 0.f;
        for (int j = s0 + hl; j < s1; j += 32)
            ssum += __expf(lrelu2(asrc[bN + csr_row[bE + j]] + adv) - m);
        ssum = hsum(ssum);
        float inv = 1.f / (ssum + 1e-16f);
        float x0 = 0.f, x1 = 0.f, x2 = 0.f, x3 = 0.f;
        for (int j = s0; j < s1; ++j) {
            int r = csr_row[bE + j];
            float wj = __expf(lrelu2(asrc[bN + r] + adv) - m) * inv;
            f16x4 h = *(const f16x4*)(Hp + (size_t)(bN + r) * CC + hl * 4);
            x0 = fmaf(wj, (float)h[0], x0);
            x1 = fmaf(wj, (float)h[1], x1);
            x2 = fmaf(wj, (float)h[2], x2);
            x3 = fmaf(wj, (float)h[3], x3);
        }
        float4 bb = ((const float4*)bias)[hl];
        float t0 = x0 + bb.x, t1 = x1 + bb.y, t2 = x2 + bb.z, t3 = x3 + bb.w;
        float4 w4 = ((const float4*)Wout)[hl];
        float p = lrelu01(t0) * w4.x + lrelu01(t1) * w4.y
                + lrelu01(t2) * w4.z + lrelu01(t3) * w4.w;
        p = hsum(p);
        if (hl == 0) pscal[g] = p;
    }
}

__global__ __launch_bounds__(256) void k_out_agg(
    const float* __restrict__ p, const float* __restrict__ dinv,
    const int* __restrict__ rowptr, const int* __restrict__ csr_row,
    const float* __restrict__ bout, float* __restrict__ gv) {
    int wid = threadIdx.x >> 6, lane = threadIdx.x & 63;
    int g = xcd_swz(blockIdx.x, gridDim.x) * 4 + wid;
    int b = g / NN, v = g - b * NN;
    int s0 = rowptr[b * RP + v], s1 = rowptr[b * RP + v + 1];
    float acc = 0.f;
    for (int j = s0 + lane; j < s1; j += 64) {
        int r = csr_row[b * ET + j];
        acc += dinv[b * NN + r] * p[b * NN + r];
    }
    acc = wsum(acc);
    if (lane == 0) gv[g] = lrelu01(acc * dinv[g] + bout[0]);
}

__global__ __launch_bounds__(128) void k_fc(
    const float* __restrict__ gv, const float* __restrict__ W1,
    const float* __restrict__ b1, const float* __restrict__ W2,
    const float* __restrict__ b2, float* __restrict__ outp) {
    __shared__ float gs[NN];
    __shared__ float s1[CC];
    int b = blockIdx.x, tx = threadIdx.x;
    for (int v = tx; v < NN; v += 128) gs[v] = gv[b * NN + v];
    __syncthreads();
    float acc = 0.f;
    for (int v = 0; v < NN; ++v) acc = fmaf(gs[v], W1[v * CC + tx], acc);
    float t = lrelu01(acc + b1[tx]);
    s1[tx] = t;
    __syncthreads();
    float acc2 = 0.f;
#pragma unroll
    for (int k = 0; k < CC; ++k) acc2 = fmaf(s1[k], W2[k * CC + tx], acc2);
    outp[b * CC + tx] = acc2 + b2[tx];
}

extern "C" void kernel_launch(void* const* d_in, const int* in_sizes, int n_in,
                              void* d_out, int out_size, void* d_ws, size_t ws_size,
                              hipStream_t stream) {
    const int*   feature  = (const int*)d_in[0];
    const int*   edges    = (const int*)d_in[1];
    const float* poi      = (const float*)d_in[3];
    const float* cat      = (const float*)d_in[4];
    const float* lat      = (const float*)d_in[5];
    const float* lon      = (const float*)d_in[6];
    const float* W_in     = (const float*)d_in[7];
    const float* b_in     = (const float*)d_in[8];
    const float* gat_W    = (const float*)d_in[9];
    const float* gat_asrc = (const float*)d_in[10];
    const float* gat_adst = (const float*)d_in[11];
    const float* gat_b    = (const float*)d_in[12];
    const float* W_out    = (const float*)d_in[13];
    const float* b_out    = (const float*)d_in[14];
    const float* W_fc1    = (const float*)d_in[15];
    const float* b_fc1    = (const float*)d_in[16];
    const float* W_fc2    = (const float*)d_in[17];
    const float* b_fc2    = (const float*)d_in[18];
    float* outp = (float*)d_out;

    char* ws = (char*)d_ws;
    size_t off = 0;
    auto take = [&](size_t bytes) -> char* {
        char* pp = ws + off;
        off = (off + bytes + 255) & ~(size_t)255;
        return pp;
    };
    int*   csr    = (int*)take((size_t)BB * ET * 4);
    int*   rowptr = (int*)take((size_t)BB * RP * 4);
    float* dinv   = (float*)take((size_t)NBt * 4);
    float* asrc   = (float*)take((size_t)NBt * 4);
    float* adst   = (float*)take((size_t)NBt * 4);
    float* asrc2  = (float*)take((size_t)NBt * 4);
    float* adst2  = (float*)take((size_t)NBt * 4);
    float* pscal  = (float*)take((size_t)NBt * 4);
    float* gvec   = (float*)take((size_t)NBt * 4);
    f16*   bufA   = (f16*)take((size_t)NBt * CC * 2);       // f16 node features
    f16*   bufB   = (f16*)take((size_t)NBt * CC * 2);       // f16 node features
    float* P      = (float*)take((size_t)PROJ_ROWS * CC * 4); // table projections
    f16*   BWh    = (f16*)take((size_t)KSP * 8 * 64 * 8 * 2);
    f16*   BWl    = (f16*)take((size_t)KSP * 8 * 64 * 8 * 2);
    f16*   BGh    = (f16*)take((size_t)3 * 4 * 8 * 64 * 8 * 2);
    f16*   BGl    = (f16*)take((size_t)3 * 4 * 8 * 64 * 8 * 2);
    float* wsv    = (float*)take((size_t)3 * CC * 4);
    float* wdv    = (float*)take((size_t)3 * CC * 4);

    k_build<<<BB, 1024, 0, stream>>>(edges, rowptr, csr, dinv);

    k_prep<<<(NSEG + NGAT + 3 * CC + 255) / 256, 256, 0, stream>>>(
        W_in, gat_W, gat_asrc, gat_adst, BWh, BWl, BGh, BGl, wsv, wdv);

    k_proj<<<596, 256, 0, stream>>>(poi, cat, lat, lon, BWh, BWl, P);
    k_assemble<<<NBt * 16 / 256, 256, 0, stream>>>(feature, P, bufB);

    const int GG = NBt / 32;   // 1428 blocks
    // GCN agg + first GAT gemm (layer 0)
    k_agg_gemm<2><<<GG, 256, 0, stream>>>(
        bufB, dinv, nullptr, rowptr, csr, b_in,
        BGh, BGl, wsv, wdv, bufA, asrc, adst);

    for (int i = 0; i < 3; ++i) {
        const f16* bh = BGh + (size_t)i * 4 * 8 * 64 * 8;
        const f16* bl = BGl + (size_t)i * 4 * 8 * 64 * 8;
        const float* ws_i = wsv + (size_t)i * CC;
        const float* wd_i = wdv + (size_t)i * CC;
        const float* gb = gat_b + (size_t)i * CC;
        // agg<0> on Hp (bufA) + second gemm of layer i -> bufB
        k_agg_gemm<0><<<GG, 256, 0, stream>>>(
            bufA, asrc, adst, rowptr, csr, gb,
            bh, bl, ws_i, wd_i, bufB, asrc2, adst2);
        if (i < 2) {
            const f16* bh2 = BGh + (size_t)(i + 1) * 4 * 8 * 64 * 8;
            const f16* bl2 = BGl + (size_t)(i + 1) * 4 * 8 * 64 * 8;
            const float* ws2 = wsv + (size_t)(i + 1) * CC;
            const float* wd2 = wdv + (size_t)(i + 1) * CC;
            // agg<1> on bufB + first gemm of layer i+1 -> bufA
            k_agg_gemm<1><<<GG, 256, 0, stream>>>(
                bufB, asrc2, adst2, rowptr, csr, gb,
                bh2, bl2, ws2, wd2, bufA, asrc, adst);
        } else {
            // last agg: fused W_out dot only
            k_agg_last<<<NBt / 8, 256, 0, stream>>>(
                bufB, asrc2, adst2, rowptr, csr, gb, W_out, pscal);
        }
    }

    k_out_agg<<<NBt / 4, 256, 0, stream>>>(pscal, dinv, rowptr, csr, b_out, gvec);
    k_fc<<<BB, 128, 0, stream>>>(gvec, W_fc1, b_fc1, W_fc2, b_fc2, outp);
}

// Round 14
// 308.803 us; speedup vs baseline: 1.0389x; 1.0389x over previous
//
#include <hip/hip_runtime.h>

// UserGraphNet: B=64 graphs, n=714 nodes, E=16384 edges (+n self loops), C=128.
// Round 13: fused agg+GEMM with FIXED parallelism — 1024-thread blocks, 16 waves
// x 2 nodes/wave = 32 nodes in ONE parallel agg pass (round 12 had 256 threads
// and 4 serial rounds -> occupancy collapse). __launch_bounds__(1024,2) keeps
// 32 waves/CU. Phase B: 8 waves run the 32-row MFMA GEMM. f16 features, fused
// CSR build, table-projection embed, fused W_out dot, XCD swizzle.

#define BB 64
#define NN 714
#define EE 16384
#define ET (EE + NN)          // 17098 edges incl self loops
#define NBt (BB * NN)         // 45696 total nodes
#define CC 128
#define RP (NN + 1)           // rowptr entries per graph
#define DFAST 64              // max degree on the half-wave fast path (deg~24)
#define KSP 28                // total padded k-steps across 4 table projections
#define PROJ_ROWS 19021       // 5099 + 400 + 7128 + 6394

typedef _Float16 f16;
typedef __attribute__((ext_vector_type(8))) _Float16 f16x8;
typedef __attribute__((ext_vector_type(4))) _Float16 f16x4;
typedef __attribute__((ext_vector_type(4))) float f32x4;

__device__ __forceinline__ float lrelu01(float x) { return x > 0.f ? x : 0.01f * x; }
__device__ __forceinline__ float lrelu2(float x)  { return x > 0.f ? x : 0.2f  * x; }

__device__ __forceinline__ float wsum(float x) {
#pragma unroll
    for (int o = 32; o > 0; o >>= 1) x += __shfl_xor(x, o);
    return x;
}
__device__ __forceinline__ float hsum(float x) {
#pragma unroll
    for (int o = 16; o > 0; o >>= 1) x += __shfl_xor(x, o);
    return x;
}
__device__ __forceinline__ float hmax(float x) {
#pragma unroll
    for (int o = 16; o > 0; o >>= 1) x = fmaxf(x, __shfl_xor(x, o));
    return x;
}

// Bijective XCD swizzle (m204)
__device__ __forceinline__ int xcd_swz(int bid, int nwg) {
    int q = nwg >> 3, r = nwg & 7;
    int x = bid & 7, l = bid >> 3;
    int base = (x < r) ? x * (q + 1) : r * (q + 1) + (x - r) * q;
    return base + l;
}

// ---- fused CSR build: one block per graph; LDS histogram + scan + scatter ----
__global__ __launch_bounds__(1024) void k_build(
    const int* __restrict__ edges, int* __restrict__ rowptr,
    int* __restrict__ csr_row, float* __restrict__ dinv) {
    __shared__ int degs[NN];
    __shared__ int scan[1024];
    __shared__ int curs[NN];
    int b = blockIdx.x, t = threadIdx.x;
    if (t < NN) degs[t] = 0;
    __syncthreads();
    int rr[17], cc[17];
#pragma unroll
    for (int q = 0; q < 17; ++q) {
        int e = q * 1024 + t;
        int r = -1, c = -1;
        if (e < ET) {
            if (e < EE) { r = edges[b * 2 * EE + e]; c = edges[b * 2 * EE + EE + e]; }
            else        { r = c = e - EE; }
            atomicAdd(&degs[c], 1);
        }
        rr[q] = r; cc[q] = c;
    }
    __syncthreads();
    int cnt = (t < NN) ? degs[t] : 0;
    scan[t] = cnt;
    __syncthreads();
    for (int off = 1; off < 1024; off <<= 1) {
        int val = (t >= off) ? scan[t - off] : 0;
        __syncthreads();
        scan[t] += val;
        __syncthreads();
    }
    if (t < NN) {
        rowptr[b * RP + t + 1] = scan[t];
        curs[t] = scan[t] - cnt;                       // exclusive prefix
        dinv[b * NN + t] = cnt > 0 ? rsqrtf((float)cnt) : 0.f;
    }
    if (t == 0) rowptr[b * RP] = 0;
    __syncthreads();
#pragma unroll
    for (int q = 0; q < 17; ++q) {
        if (cc[q] >= 0) {
            int slot = atomicAdd(&curs[cc[q]], 1);     // LDS atomic
            csr_row[b * ET + slot] = rr[q];
        }
    }
}

// ---- merged prep: pack W_in table-slices, pack gat_W, compute w_s/w_d ----
#define NSEG (KSP * 8 * 64)
#define NGAT (3 * 4 * 8 * 64)
__global__ void k_prep(const float* __restrict__ W, const float* __restrict__ gat_W,
                       const float* __restrict__ a_s, const float* __restrict__ a_d,
                       f16* __restrict__ BWh, f16* __restrict__ BWl,
                       f16* __restrict__ BGh, f16* __restrict__ BGl,
                       float* __restrict__ wsv, float* __restrict__ wdv) {
    int idx = blockIdx.x * 256 + threadIdx.x;
    if (idx < NSEG) {
        int lane = idx & 63, tc = idx >> 6;
        int ct = tc & 7, ks = tc >> 3;
        int t  = ks < 10 ? 0 : ks < 14 ? 1 : ks < 21 ? 2 : 3;
        int k0 = t == 0 ? 0 : t == 1 ? 10 : t == 2 ? 14 : 21;
        const int Ktab[4] = {300, 100, 200, 200};
        const int Koff[4] = {0, 300, 400, 600};
        int ksl = ks - k0;
        f16x8 ph, pl;
#pragma unroll
        for (int j = 0; j < 8; ++j) {
            int k = ksl * 32 + (lane >> 4) * 8 + j;
            int c = ct * 16 + (lane & 15);
            float v = (k < Ktab[t]) ? W[(size_t)(Koff[t] + k) * CC + c] : 0.f;
            f16 hi = (f16)v;
            ph[j] = hi; pl[j] = (f16)(v - (float)hi);
        }
        *(f16x8*)(BWh + (size_t)idx * 8) = ph;
        *(f16x8*)(BWl + (size_t)idx * 8) = pl;
    } else if (idx < NSEG + NGAT) {
        int i2 = idx - NSEG;
        int lane = i2 & 63, tc = i2 >> 6;
        int ct = tc & 7; tc >>= 3;
        int ks = tc & 3, li = tc >> 2;
        const float* Wl = gat_W + (size_t)li * CC * CC;
        f16x8 ph, pl;
#pragma unroll
        for (int j = 0; j < 8; ++j) {
            int k = ks * 32 + (lane >> 4) * 8 + j;
            int c = ct * 16 + (lane & 15);
            float v = Wl[k * CC + c];
            f16 hi = (f16)v;
            ph[j] = hi; pl[j] = (f16)(v - (float)hi);
        }
        *(f16x8*)(BGh + (size_t)i2 * 8) = ph;
        *(f16x8*)(BGl + (size_t)i2 * 8) = pl;
    } else if (idx < NSEG + NGAT + 3 * CC) {
        int i2 = idx - NSEG - NGAT;
        int i = i2 >> 7, k = i2 & 127;
        const float* Wl = gat_W + (size_t)i * CC * CC;
        float s = 0.f, d = 0.f;
#pragma unroll 4
        for (int c = 0; c < CC; ++c) {
            float w = Wl[k * CC + c];
            s = fmaf(w, a_s[i * CC + c], s);
            d = fmaf(w, a_d[i * CC + c], d);
        }
        wsv[i * CC + k] = s; wdv[i * CC + k] = d;
    }
}

// ---- table-projection GEMM: P[t] = table[t] @ W_in[Koff:Koff+K]  (f32 out) ----
__global__ __launch_bounds__(256) void k_proj(
    const float* __restrict__ poi, const float* __restrict__ cat,
    const float* __restrict__ lat, const float* __restrict__ lon,
    const f16* __restrict__ Bh, const f16* __restrict__ Bl,
    float* __restrict__ P) {
    int bid = blockIdx.x;
    int t, r0;
    if (bid < 160)      { t = 0; r0 = bid * 32; }
    else if (bid < 173) { t = 1; r0 = (bid - 160) * 32; }
    else if (bid < 396) { t = 2; r0 = (bid - 173) * 32; }
    else                { t = 3; r0 = (bid - 396) * 32; }
    const int Ktab[4] = {300, 100, 200, 200};
    const int Rtab[4] = {5099, 400, 7128, 6394};
    const int Rofs[4] = {0, 5099, 5499, 12627};
    const int Kst[4]  = {10, 4, 7, 7};
    const int Bks0[4] = {0, 10, 14, 21};
    const float* tab = t == 0 ? poi : t == 1 ? cat : t == 2 ? lat : lon;
    int K = Ktab[t], R = Rtab[t], nks = Kst[t], bks = Bks0[t];
    int lane = threadIdx.x & 63, w = threadIdx.x >> 6;
    int ct0 = w * 2;
    f32x4 acc[2][2];
#pragma unroll
    for (int rt = 0; rt < 2; ++rt)
#pragma unroll
        for (int c = 0; c < 2; ++c) acc[rt][c] = (f32x4){0.f, 0.f, 0.f, 0.f};

    for (int ks = 0; ks < nks; ++ks) {
        int kbase = ks * 32 + (lane >> 4) * 8;
        f16x8 ah[2], al[2];
#pragma unroll
        for (int rt = 0; rt < 2; ++rt) {
            int row = r0 + rt * 16 + (lane & 15);
            int rowc = row < R ? row : R - 1;
            const float* rp = tab + (size_t)rowc * K;
            float v[8];
            if (kbase + 8 <= K) {
                float4 x0 = ((const float4*)(rp + kbase))[0];
                float4 x1 = ((const float4*)(rp + kbase))[1];
                v[0] = x0.x; v[1] = x0.y; v[2] = x0.z; v[3] = x0.w;
                v[4] = x1.x; v[5] = x1.y; v[6] = x1.z; v[7] = x1.w;
            } else if (kbase >= K) {
#pragma unroll
                for (int m = 0; m < 8; ++m) v[m] = 0.f;
            } else {
#pragma unroll
                for (int m = 0; m < 8; ++m) v[m] = (kbase + m < K) ? rp[kbase + m] : 0.f;
            }
#pragma unroll
            for (int j = 0; j < 8; ++j) {
                f16 hi = (f16)v[j];
                ah[rt][j] = hi; al[rt][j] = (f16)(v[j] - (float)hi);
            }
        }
#pragma unroll
        for (int cti = 0; cti < 2; ++cti) {
            int ct = ct0 + cti;
            f16x8 bh = *(const f16x8*)(Bh + ((size_t)((bks + ks) * 8 + ct) * 64 + lane) * 8);
            f16x8 bl = *(const f16x8*)(Bl + ((size_t)((bks + ks) * 8 + ct) * 64 + lane) * 8);
#pragma unroll
            for (int rt = 0; rt < 2; ++rt) {
                acc[rt][cti] = __builtin_amdgcn_mfma_f32_16x16x32_f16(ah[rt], bh, acc[rt][cti], 0, 0, 0);
                acc[rt][cti] = __builtin_amdgcn_mfma_f32_16x16x32_f16(al[rt], bh, acc[rt][cti], 0, 0, 0);
                acc[rt][cti] = __builtin_amdgcn_mfma_f32_16x16x32_f16(ah[rt], bl, acc[rt][cti], 0, 0, 0);
            }
        }
    }
#pragma unroll
    for (int rt = 0; rt < 2; ++rt)
#pragma unroll
        for (int cti = 0; cti < 2; ++cti)
#pragma unroll
            for (int i = 0; i < 4; ++i) {
                int row = r0 + rt * 16 + (lane >> 4) * 4 + i;
                if (row < R) {
                    int col = (ct0 + cti) * 16 + (lane & 15);
                    P[(size_t)(Rofs[t] + row) * CC + col] = acc[rt][cti][i];
                }
            }
}

// ---- per-node assembly: bufB[g] = P_poi[f0] + P_cat[f1] + P_lat[f3] + P_lon[f4] ----
__global__ __launch_bounds__(256) void k_assemble(
    const int* __restrict__ feature, const float* __restrict__ P,
    f16* __restrict__ out) {
    int tid = xcd_swz(blockIdx.x, gridDim.x) * 256 + threadIdx.x;
    int g = tid >> 4, c8 = (tid & 15) * 8;
    const int* f = feature + (size_t)g * 5;
    const float4* p0 = (const float4*)(P + (size_t)f[0] * CC + c8);
    const float4* p1 = (const float4*)(P + (size_t)(5099 + f[1]) * CC + c8);
    const float4* p2 = (const float4*)(P + (size_t)(5499 + f[3]) * CC + c8);
    const float4* p3 = (const float4*)(P + (size_t)(12627 + f[4]) * CC + c8);
    float4 a0 = p0[0], a1 = p0[1];
    float4 b0 = p1[0], b1 = p1[1];
    float4 c0 = p2[0], c1 = p2[1];
    float4 d0 = p3[0], d1 = p3[1];
    f16x8 r;
    r[0] = (f16)(a0.x + b0.x + c0.x + d0.x);
    r[1] = (f16)(a0.y + b0.y + c0.y + d0.y);
    r[2] = (f16)(a0.z + b0.z + c0.z + d0.z);
    r[3] = (f16)(a0.w + b0.w + c0.w + d0.w);
    r[4] = (f16)(a1.x + b1.x + c1.x + d1.x);
    r[5] = (f16)(a1.y + b1.y + c1.y + d1.y);
    r[6] = (f16)(a1.z + b1.z + c1.z + d1.z);
    r[7] = (f16)(a1.w + b1.w + c1.w + d1.w);
    *(f16x8*)(out + (size_t)g * CC + c8) = r;
}

// ---- FUSED aggregate + GEMM: 1024-thread block = 32 nodes, ONE agg pass ----
// Phase A: 16 waves x 2 nodes (register softmax) -> swizzled LDS A-tile + next
// asrc/adst. Phase B: waves 0-7 run the 32-row MFMA GEMM -> Hp (f16).
// MODE 2: GCN (aux=dinv). MODE 0: GAT h=lrelu01(t)+t. MODE 1: GAT h=lrelu01(t).
template <int MODE>
__global__ __launch_bounds__(1024, 2) void k_agg_gemm(
    const f16* __restrict__ Hin, const float* __restrict__ aux,
    const float* __restrict__ adst, const int* __restrict__ rowptr,
    const int* __restrict__ csr_row, const float* __restrict__ bias,
    const f16* __restrict__ Bh, const f16* __restrict__ Bl,
    const float* __restrict__ wsv, const float* __restrict__ wdv,
    f16* __restrict__ Hp, float* __restrict__ asrc_o, float* __restrict__ adst_o) {
    __shared__ __align__(16) f16 Ah[32 * 128];
    __shared__ float2 pr[16][2][DFAST];
    int t = threadIdx.x;
    int wid = t >> 6, lane = t & 63;
    int half = lane >> 5, hl = lane & 31;
    int g0 = xcd_swz(blockIdx.x, gridDim.x) * 32;
    int ln = wid * 2 + half;                       // local node 0..31
    int g = g0 + ln;
    int b = g / NN, v = g - b * NN;
    int bN = b * NN, bE = b * ET;
    int s0 = rowptr[b * RP + v], s1 = rowptr[b * RP + v + 1];
    int deg = s1 - s0;

    // ================= Phase A: aggregate (one parallel pass) =================
    if (deg <= DFAST) {
        int degp = (deg + 7) & ~7;
        float inv = 1.f;
        int r0i = 0, r1i = 0;
        float w0v, w1v;
        if (MODE == 2) {
            float dv = aux[g];
            w0v = w1v = 0.f;
            if (hl < deg)      { r0i = csr_row[bE + s0 + hl];      w0v = aux[bN + r0i] * dv; }
            if (hl + 32 < deg) { r1i = csr_row[bE + s0 + hl + 32]; w1v = aux[bN + r1i] * dv; }
        } else {
            float adv = adst[g];
            float e0 = -3.0e38f, e1 = -3.0e38f;
            if (hl < deg)      { r0i = csr_row[bE + s0 + hl];      e0 = lrelu2(aux[bN + r0i] + adv); }
            if (hl + 32 < deg) { r1i = csr_row[bE + s0 + hl + 32]; e1 = lrelu2(aux[bN + r1i] + adv); }
            float m = hmax(fmaxf(e0, e1));
            w0v = __expf(e0 - m);
            w1v = __expf(e1 - m);
            float ss = hsum(w0v + w1v);
            inv = 1.f / (ss + 1e-16f);
        }
        if (hl < degp)      pr[wid][half][hl]      = make_float2(w0v, __int_as_float(r0i));
        if (hl + 32 < degp) pr[wid][half][hl + 32] = make_float2(w1v, __int_as_float(r1i));
        // same-wave DS ordering: phase-2 reads see these writes
        int eh = hl >> 4, ql = hl & 15;
        const f16* Hb = Hin + (size_t)bN * CC;
        float acc0[8], acc1[8], acc2[8], acc3[8];
#pragma unroll
        for (int j = 0; j < 8; ++j) { acc0[j] = 0.f; acc1[j] = 0.f; acc2[j] = 0.f; acc3[j] = 0.f; }
        for (int jj = 0; jj < degp; jj += 8) {
            float2 p0 = pr[wid][half][jj + eh];
            float2 p1 = pr[wid][half][jj + 2 + eh];
            float2 p2 = pr[wid][half][jj + 4 + eh];
            float2 p3 = pr[wid][half][jj + 6 + eh];
            f16x8 h0 = *(const f16x8*)(Hb + (size_t)__float_as_int(p0.y) * CC + ql * 8);
            f16x8 h1 = *(const f16x8*)(Hb + (size_t)__float_as_int(p1.y) * CC + ql * 8);
            f16x8 h2 = *(const f16x8*)(Hb + (size_t)__float_as_int(p2.y) * CC + ql * 8);
            f16x8 h3 = *(const f16x8*)(Hb + (size_t)__float_as_int(p3.y) * CC + ql * 8);
#pragma unroll
            for (int j = 0; j < 8; ++j) {
                acc0[j] = fmaf((float)h0[j], p0.x, acc0[j]);
                acc1[j] = fmaf((float)h1[j], p1.x, acc1[j]);
                acc2[j] = fmaf((float)h2[j], p2.x, acc2[j]);
                acc3[j] = fmaf((float)h3[j], p3.x, acc3[j]);
            }
        }
        float ov[8];
        float sc = (MODE == 2) ? 1.f : inv;
        float4 bb0 = ((const float4*)bias)[ql * 2];
        float4 bb1 = ((const float4*)bias)[ql * 2 + 1];
#pragma unroll
        for (int j = 0; j < 8; ++j) {
            float x = acc0[j] + acc1[j] + acc2[j] + acc3[j];
            x += __shfl_xor(x, 16);                // both eh groups now hold sum
            float bv = (j < 4) ? ((const float*)&bb0)[j] : ((const float*)&bb1)[j - 4];
            float tv = x * sc + bv;
            float l = lrelu01(tv);
            ov[j] = (MODE == 0) ? l + tv : l;
        }
        // next-layer asrc/adst: dot(ov, wsv/wdv) over this lane's 8 cols
        float ps = 0.f, pd = 0.f;
#pragma unroll
        for (int j = 0; j < 8; ++j) {
            ps = fmaf(ov[j], wsv[ql * 8 + j], ps);
            pd = fmaf(ov[j], wdv[ql * 8 + j], pd);
        }
#pragma unroll
        for (int o = 8; o > 0; o >>= 1) {
            ps += __shfl_xor(ps, o);
            pd += __shfl_xor(pd, o);
        }
        if (hl == 0) { asrc_o[g] = ps; adst_o[g] = pd; }
        if (eh == 0) {
            f16x8 r;
#pragma unroll
            for (int j = 0; j < 8; ++j) r[j] = (f16)ov[j];
            *(f16x8*)&Ah[ln * 128 + ((ql ^ (ln & 7)) << 3)] = r;
        }
    } else {
        // fallback deg > DFAST (half-wave, 4 cols/lane); ~never taken
        float wsc0 = 0.f, m = 0.f, inv = 1.f, adv = 0.f;
        if (MODE != 2) {
            adv = adst[g];
            m = -3.0e38f;
            for (int j = s0 + hl; j < s1; j += 32)
                m = fmaxf(m, lrelu2(aux[bN + csr_row[bE + j]] + adv));
            m = hmax(m);
            float ssum = 0.f;
            for (int j = s0 + hl; j < s1; j += 32)
                ssum += __expf(lrelu2(aux[bN + csr_row[bE + j]] + adv) - m);
            ssum = hsum(ssum);
            inv = 1.f / (ssum + 1e-16f);
        } else {
            wsc0 = aux[g];
        }
        float x0 = 0.f, x1 = 0.f, x2 = 0.f, x3 = 0.f;
        for (int j = s0; j < s1; ++j) {
            int r = csr_row[bE + j];
            float wj = (MODE == 2) ? aux[bN + r]
                                   : __expf(lrelu2(aux[bN + r] + adv) - m) * inv;
            f16x4 h = *(const f16x4*)(Hin + (size_t)(bN + r) * CC + hl * 4);
            x0 = fmaf(wj, (float)h[0], x0);
            x1 = fmaf(wj, (float)h[1], x1);
            x2 = fmaf(wj, (float)h[2], x2);
            x3 = fmaf(wj, (float)h[3], x3);
        }
        if (MODE == 2) { x0 *= wsc0; x1 *= wsc0; x2 *= wsc0; x3 *= wsc0; }
        float4 bb = ((const float4*)bias)[hl];
        float t0 = x0 + bb.x, t1 = x1 + bb.y, t2 = x2 + bb.z, t3 = x3 + bb.w;
        float o0 = (MODE == 0) ? lrelu01(t0) + t0 : lrelu01(t0);
        float o1 = (MODE == 0) ? lrelu01(t1) + t1 : lrelu01(t1);
        float o2 = (MODE == 0) ? lrelu01(t2) + t2 : lrelu01(t2);
        float o3 = (MODE == 0) ? lrelu01(t3) + t3 : lrelu01(t3);
        float4 wsv4 = ((const float4*)wsv)[hl];
        float4 wdv4 = ((const float4*)wdv)[hl];
        float ps = o0 * wsv4.x + o1 * wsv4.y + o2 * wsv4.z + o3 * wsv4.w;
        float pd = o0 * wdv4.x + o1 * wdv4.y + o2 * wdv4.z + o3 * wdv4.w;
        ps = hsum(ps); pd = hsum(pd);
        if (hl == 0) { asrc_o[g] = ps; adst_o[g] = pd; }
        int kg = hl >> 1;
        f16x4 r;
        r[0] = (f16)o0; r[1] = (f16)o1; r[2] = (f16)o2; r[3] = (f16)o3;
        *(f16x4*)&Ah[ln * 128 + ((kg ^ (ln & 7)) << 3) + (hl & 1) * 4] = r;
    }
    __syncthreads();

    // ================= Phase B: 32-row MFMA GEMM (waves 0..7) =================
    if (wid < 8) {
        int ct = wid;
        f32x4 acc[2];
#pragma unroll
        for (int rt = 0; rt < 2; ++rt) acc[rt] = (f32x4){0.f, 0.f, 0.f, 0.f};
#pragma unroll
        for (int ks = 0; ks < 4; ++ks) {
            f16x8 ahf[2];
#pragma unroll
            for (int rt = 0; rt < 2; ++rt) {
                int r = rt * 16 + (lane & 15);
                int kg = (lane >> 4) + ks * 4;
                int ad = r * 128 + ((kg ^ (r & 7)) << 3);
                ahf[rt] = *(const f16x8*)&Ah[ad];
            }
            f16x8 bh = *(const f16x8*)(Bh + ((size_t)(ks * 8 + ct) * 64 + lane) * 8);
            f16x8 bl = *(const f16x8*)(Bl + ((size_t)(ks * 8 + ct) * 64 + lane) * 8);
#pragma unroll
            for (int rt = 0; rt < 2; ++rt) {
                acc[rt] = __builtin_amdgcn_mfma_f32_16x16x32_f16(ahf[rt], bh, acc[rt], 0, 0, 0);
                acc[rt] = __builtin_amdgcn_mfma_f32_16x16x32_f16(ahf[rt], bl, acc[rt], 0, 0, 0);
            }
        }
#pragma unroll
        for (int rt = 0; rt < 2; ++rt)
#pragma unroll
            for (int i = 0; i < 4; ++i) {
                int row = g0 + rt * 16 + (lane >> 4) * 4 + i;
                int col = ct * 16 + (lane & 15);
                Hp[(size_t)row * CC + col] = (f16)acc[rt][i];
            }
    }
}

// ---- final standalone aggregate: softmax agg + fused W_out dot ----
__global__ __launch_bounds__(256) void k_agg_last(
    const f16* __restrict__ Hp, const float* __restrict__ asrc,
    const float* __restrict__ adst, const int* __restrict__ rowptr,
    const int* __restrict__ csr_row, const float* __restrict__ bias,
    const float* __restrict__ Wout, float* __restrict__ pscal) {
    __shared__ float2 pr[4][2][DFAST];
    int wid = threadIdx.x >> 6, lane = threadIdx.x & 63;
    int half = lane >> 5, hl = lane & 31;
    int g = xcd_swz(blockIdx.x, gridDim.x) * 8 + wid * 2 + half;
    int b = g / NN, v = g - b * NN;
    int bN = b * NN, bE = b * ET;
    int s0 = rowptr[b * RP + v], s1 = rowptr[b * RP + v + 1];
    int deg = s1 - s0;

    if (deg <= DFAST) {
        int degp = (deg + 7) & ~7;
        float adv = adst[g];
        float e0 = -3.0e38f, e1 = -3.0e38f;
        int r0i = 0, r1i = 0;
        if (hl < deg)      { r0i = csr_row[bE + s0 + hl];      e0 = lrelu2(asrc[bN + r0i] + adv); }
        if (hl + 32 < deg) { r1i = csr_row[bE + s0 + hl + 32]; e1 = lrelu2(asrc[bN + r1i] + adv); }
        float m = hmax(fmaxf(e0, e1));
        float w0v = __expf(e0 - m), w1v = __expf(e1 - m);
        float ss = hsum(w0v + w1v);
        float inv = 1.f / (ss + 1e-16f);
        if (hl < degp)      pr[wid][half][hl]      = make_float2(w0v, __int_as_float(r0i));
        if (hl + 32 < degp) pr[wid][half][hl + 32] = make_float2(w1v, __int_as_float(r1i));
        int eh = hl >> 4, ql = hl & 15;
        const f16* Hb = Hp + (size_t)bN * CC;
        float acc0[8], acc1[8], acc2[8], acc3[8];
#pragma unroll
        for (int j = 0; j < 8; ++j) { acc0[j] = 0.f; acc1[j] = 0.f; acc2[j] = 0.f; acc3[j] = 0.f; }
        for (int jj = 0; jj < degp; jj += 8) {
            float2 p0 = pr[wid][half][jj + eh];
            float2 p1 = pr[wid][half][jj + 2 + eh];
            float2 p2 = pr[wid][half][jj + 4 + eh];
            float2 p3 = pr[wid][half][jj + 6 + eh];
            f16x8 h0 = *(const f16x8*)(Hb + (size_t)__float_as_int(p0.y) * CC + ql * 8);
            f16x8 h1 = *(const f16x8*)(Hb + (size_t)__float_as_int(p1.y) * CC + ql * 8);
            f16x8 h2 = *(const f16x8*)(Hb + (size_t)__float_as_int(p2.y) * CC + ql * 8);
            f16x8 h3 = *(const f16x8*)(Hb + (size_t)__float_as_int(p3.y) * CC + ql * 8);
#pragma unroll
            for (int j = 0; j < 8; ++j) {
                acc0[j] = fmaf((float)h0[j], p0.x, acc0[j]);
                acc1[j] = fmaf((float)h1[j], p1.x, acc1[j]);
                acc2[j] = fmaf((float)h2[j], p2.x, acc2[j]);
                acc3[j] = fmaf((float)h3[j], p3.x, acc3[j]);
            }
        }
        float4 bb0 = ((const float4*)bias)[ql * 2];
        float4 bb1 = ((const float4*)bias)[ql * 2 + 1];
        float4 w0 = ((const float4*)Wout)[ql * 2];
        float4 w1 = ((const float4*)Wout)[ql * 2 + 1];
        float p = 0.f;
#pragma unroll
        for (int j = 0; j < 8; ++j) {
            float x = acc0[j] + acc1[j] + acc2[j] + acc3[j];
            x += __shfl_xor(x, 16);
            float bv = (j < 4) ? ((const float*)&bb0)[j] : ((const float*)&bb1)[j - 4];
            float wv = (j < 4) ? ((const float*)&w0)[j] : ((const float*)&w1)[j - 4];
            float tv = x * inv + bv;
            p = fmaf(lrelu01(tv), wv, p);
        }
#pragma unroll
        for (int o = 8; o > 0; o >>= 1) p += __shfl_xor(p, o);
        if (hl == 0) pscal[g] = p;
        return;
    }
    // fallback deg > DFAST
    {
        float adv = adst[g];
        float m = -3.0e38f;
        for (int j = s0 + hl; j < s1; j += 32)
            m = fmaxf(m, lrelu2(asrc[bN + csr_row[bE + j]] + adv));
        m = hmax(m);
        float ssum = 0.f;
        for (int j = s0 + hl; j < s1; j += 32)
            ssum += __expf(lrelu2(asrc[bN + csr_row[bE + j]] + adv) - m);
        ssum = hsum(ssum);
        float inv = 1.f / (ssum + 1e-16f);
        float x0 = 0.f, x1 = 0.f, x2 = 0.f, x3 = 0.f;
        for (int j = s0; j < s1; ++j) {
            int r = csr_row[bE + j];
            float wj = __expf(lrelu2(asrc[bN + r] + adv) - m) * inv;
            f16x4 h = *(const f16x4*)(Hp + (size_t)(bN + r) * CC + hl * 4);
            x0 = fmaf(wj, (float)h[0], x0);
            x1 = fmaf(wj, (float)h[1], x1);
            x2 = fmaf(wj, (float)h[2], x2);
            x3 = fmaf(wj, (float)h[3], x3);
        }
        float4 bb = ((const float4*)bias)[hl];
        float t0 = x0 + bb.x, t1 = x1 + bb.y, t2 = x2 + bb.z, t3 = x3 + bb.w;
        float4 w4 = ((const float4*)Wout)[hl];
        float p = lrelu01(t0) * w4.x + lrelu01(t1) * w4.y
                + lrelu01(t2) * w4.z + lrelu01(t3) * w4.w;
        p = hsum(p);
        if (hl == 0) pscal[g] = p;
    }
}

__global__ __launch_bounds__(256) void k_out_agg(
    const float* __restrict__ p, const float* __restrict__ dinv,
    const int* __restrict__ rowptr, const int* __restrict__ csr_row,
    const float* __restrict__ bout, float* __restrict__ gv) {
    int wid = threadIdx.x >> 6, lane = threadIdx.x & 63;
    int g = xcd_swz(blockIdx.x, gridDim.x) * 4 + wid;
    int b = g / NN, v = g - b * NN;
    int s0 = rowptr[b * RP + v], s1 = rowptr[b * RP + v + 1];
    float acc = 0.f;
    for (int j = s0 + lane; j < s1; j += 64) {
        int r = csr_row[b * ET + j];
        acc += dinv[b * NN + r] * p[b * NN + r];
    }
    acc = wsum(acc);
    if (lane == 0) gv[g] = lrelu01(acc * dinv[g] + bout[0]);
}

__global__ __launch_bounds__(128) void k_fc(
    const float* __restrict__ gv, const float* __restrict__ W1,
    const float* __restrict__ b1, const float* __restrict__ W2,
    const float* __restrict__ b2, float* __restrict__ outp) {
    __shared__ float gs[NN];
    __shared__ float s1[CC];
    int b = blockIdx.x, tx = threadIdx.x;
    for (int v = tx; v < NN; v += 128) gs[v] = gv[b * NN + v];
    __syncthreads();
    float acc = 0.f;
    for (int v = 0; v < NN; ++v) acc = fmaf(gs[v], W1[v * CC + tx], acc);
    float t = lrelu01(acc + b1[tx]);
    s1[tx] = t;
    __syncthreads();
    float acc2 = 0.f;
#pragma unroll
    for (int k = 0; k < CC; ++k) acc2 = fmaf(s1[k], W2[k * CC + tx], acc2);
    outp[b * CC + tx] = acc2 + b2[tx];
}

extern "C" void kernel_launch(void* const* d_in, const int* in_sizes, int n_in,
                              void* d_out, int out_size, void* d_ws, size_t ws_size,
                              hipStream_t stream) {
    const int*   feature  = (const int*)d_in[0];
    const int*   edges    = (const int*)d_in[1];
    const float* poi      = (const float*)d_in[3];
    const float* cat      = (const float*)d_in[4];
    const float* lat      = (const float*)d_in[5];
    const float* lon      = (const float*)d_in[6];
    const float* W_in     = (const float*)d_in[7];
    const float* b_in     = (const float*)d_in[8];
    const float* gat_W    = (const float*)d_in[9];
    const float* gat_asrc = (const float*)d_in[10];
    const float* gat_adst = (const float*)d_in[11];
    const float* gat_b    = (const float*)d_in[12];
    const float* W_out    = (const float*)d_in[13];
    const float* b_out    = (const float*)d_in[14];
    const float* W_fc1    = (const float*)d_in[15];
    const float* b_fc1    = (const float*)d_in[16];
    const float* W_fc2    = (const float*)d_in[17];
    const float* b_fc2    = (const float*)d_in[18];
    float* outp = (float*)d_out;

    char* ws = (char*)d_ws;
    size_t off = 0;
    auto take = [&](size_t bytes) -> char* {
        char* pp = ws + off;
        off = (off + bytes + 255) & ~(size_t)255;
        return pp;
    };
    int*   csr    = (int*)take((size_t)BB * ET * 4);
    int*   rowptr = (int*)take((size_t)BB * RP * 4);
    float* dinv   = (float*)take((size_t)NBt * 4);
    float* asrc   = (float*)take((size_t)NBt * 4);
    float* adst   = (float*)take((size_t)NBt * 4);
    float* asrc2  = (float*)take((size_t)NBt * 4);
    float* adst2  = (float*)take((size_t)NBt * 4);
    float* pscal  = (float*)take((size_t)NBt * 4);
    float* gvec   = (float*)take((size_t)NBt * 4);
    f16*   bufA   = (f16*)take((size_t)NBt * CC * 2);       // f16 node features
    f16*   bufB   = (f16*)take((size_t)NBt * CC * 2);       // f16 node features
    float* P      = (float*)take((size_t)PROJ_ROWS * CC * 4); // table projections
    f16*   BWh    = (f16*)take((size_t)KSP * 8 * 64 * 8 * 2);
    f16*   BWl    = (f16*)take((size_t)KSP * 8 * 64 * 8 * 2);
    f16*   BGh    = (f16*)take((size_t)3 * 4 * 8 * 64 * 8 * 2);
    f16*   BGl    = (f16*)take((size_t)3 * 4 * 8 * 64 * 8 * 2);
    float* wsv    = (float*)take((size_t)3 * CC * 4);
    float* wdv    = (float*)take((size_t)3 * CC * 4);

    k_build<<<BB, 1024, 0, stream>>>(edges, rowptr, csr, dinv);

    k_prep<<<(NSEG + NGAT + 3 * CC + 255) / 256, 256, 0, stream>>>(
        W_in, gat_W, gat_asrc, gat_adst, BWh, BWl, BGh, BGl, wsv, wdv);

    k_proj<<<596, 256, 0, stream>>>(poi, cat, lat, lon, BWh, BWl, P);
    k_assemble<<<NBt * 16 / 256, 256, 0, stream>>>(feature, P, bufB);

    const int GG = NBt / 32;   // 1428 blocks x 1024 threads
    // GCN agg + first GAT gemm (layer 0)
    k_agg_gemm<2><<<GG, 1024, 0, stream>>>(
        bufB, dinv, nullptr, rowptr, csr, b_in,
        BGh, BGl, wsv, wdv, bufA, asrc, adst);

    for (int i = 0; i < 3; ++i) {
        const f16* bh = BGh + (size_t)i * 4 * 8 * 64 * 8;
        const f16* bl = BGl + (size_t)i * 4 * 8 * 64 * 8;
        const float* ws_i = wsv + (size_t)i * CC;
        const float* wd_i = wdv + (size_t)i * CC;
        const float* gb = gat_b + (size_t)i * CC;
        // agg<0> on Hp (bufA) + second gemm of layer i -> bufB
        k_agg_gemm<0><<<GG, 1024, 0, stream>>>(
            bufA, asrc, adst, rowptr, csr, gb,
            bh, bl, ws_i, wd_i, bufB, asrc2, adst2);
        if (i < 2) {
            const f16* bh2 = BGh + (size_t)(i + 1) * 4 * 8 * 64 * 8;
            const f16* bl2 = BGl + (size_t)(i + 1) * 4 * 8 * 64 * 8;
            const float* ws2 = wsv + (size_t)(i + 1) * CC;
            const float* wd2 = wdv + (size_t)(i + 1) * CC;
            // agg<1> on bufB + first gemm of layer i+1 -> bufA
            k_agg_gemm<1><<<GG, 1024, 0, stream>>>(
                bufB, asrc2, adst2, rowptr, csr, gb,
                bh2, bl2, ws2, wd2, bufA, asrc, adst);
        } else {
            // last agg: fused W_out dot only
            k_agg_last<<<NBt / 8, 256, 0, stream>>>(
                bufB, asrc2, adst2, rowptr, csr, gb, W_out, pscal);
        }
    }

    k_out_agg<<<NBt / 4, 256, 0, stream>>>(pscal, dinv, rowptr, csr, b_out, gvec);
    k_fc<<<BB, 128, 0, stream>>>(gvec, W_fc1, b_fc1, W_fc2, b_fc2, outp);
}

// Round 15
// 291.160 us; speedup vs baseline: 1.1019x; 1.0606x over previous
//
#include <hip/hip_runtime.h>

// UserGraphNet: B=64 graphs, n=714 nodes, E=16384 edges (+n self loops), C=128.
// Round 14: REVERT to round-11 split structure (fusion rounds 12/13 both lost:
// barrier + GEMM tail + LDS growth > launch/traffic savings). One cleanup: CSR
// build and weight-prep merged into a single kernel launch.
// Agg = 2 nodes/wave register softmax; f16 features end-to-end; 2-term MFMA
// GEMMs; table-projection embed; fused W_out dot; XCD swizzle.

#define BB 64
#define NN 714
#define EE 16384
#define ET (EE + NN)          // 17098 edges incl self loops
#define NBt (BB * NN)         // 45696 total nodes
#define CC 128
#define RP (NN + 1)           // rowptr entries per graph
#define DFAST 64              // max degree on the 2-node/wave fast path (deg~24)
#define KSP 28                // total padded k-steps across 4 table projections
#define PROJ_ROWS 19021       // 5099 + 400 + 7128 + 6394

typedef _Float16 f16;
typedef __attribute__((ext_vector_type(8))) _Float16 f16x8;
typedef __attribute__((ext_vector_type(4))) _Float16 f16x4;
typedef __attribute__((ext_vector_type(4))) float f32x4;

__device__ __forceinline__ float lrelu01(float x) { return x > 0.f ? x : 0.01f * x; }
__device__ __forceinline__ float lrelu2(float x)  { return x > 0.f ? x : 0.2f  * x; }

__device__ __forceinline__ float wsum(float x) {
#pragma unroll
    for (int o = 32; o > 0; o >>= 1) x += __shfl_xor(x, o);
    return x;
}
__device__ __forceinline__ float hsum(float x) {
#pragma unroll
    for (int o = 16; o > 0; o >>= 1) x += __shfl_xor(x, o);
    return x;
}
__device__ __forceinline__ float hmax(float x) {
#pragma unroll
    for (int o = 16; o > 0; o >>= 1) x = fmaxf(x, __shfl_xor(x, o));
    return x;
}

// Bijective XCD swizzle (m204)
__device__ __forceinline__ int xcd_swz(int bid, int nwg) {
    int q = nwg >> 3, r = nwg & 7;
    int x = bid & 7, l = bid >> 3;
    int base = (x < r) ? x * (q + 1) : r * (q + 1) + (x - r) * q;
    return base + l;
}

// ---- merged CSR build (blocks 0..BB-1) + weight prep (blocks BB..) ----
#define NSEG (KSP * 8 * 64)
#define NGAT (3 * 4 * 8 * 64)
#define NPREP (NSEG + NGAT + 3 * CC)
__global__ __launch_bounds__(1024) void k_build_prep(
    const int* __restrict__ edges, int* __restrict__ rowptr,
    int* __restrict__ csr_row, float* __restrict__ dinv,
    const float* __restrict__ W, const float* __restrict__ gat_W,
    const float* __restrict__ a_s, const float* __restrict__ a_d,
    f16* __restrict__ BWh, f16* __restrict__ BWl,
    f16* __restrict__ BGh, f16* __restrict__ BGl,
    float* __restrict__ wsv, float* __restrict__ wdv) {
    __shared__ int degs[NN];
    __shared__ int scan[1024];
    __shared__ int curs[NN];
    int t = threadIdx.x;
    if (blockIdx.x < BB) {
        // ---------------- CSR build ----------------
        int b = blockIdx.x;
        if (t < NN) degs[t] = 0;
        __syncthreads();
        int rr[17], cc[17];
#pragma unroll
        for (int q = 0; q < 17; ++q) {
            int e = q * 1024 + t;
            int r = -1, c = -1;
            if (e < ET) {
                if (e < EE) { r = edges[b * 2 * EE + e]; c = edges[b * 2 * EE + EE + e]; }
                else        { r = c = e - EE; }
                atomicAdd(&degs[c], 1);
            }
            rr[q] = r; cc[q] = c;
        }
        __syncthreads();
        int cnt = (t < NN) ? degs[t] : 0;
        scan[t] = cnt;
        __syncthreads();
        for (int off = 1; off < 1024; off <<= 1) {
            int val = (t >= off) ? scan[t - off] : 0;
            __syncthreads();
            scan[t] += val;
            __syncthreads();
        }
        if (t < NN) {
            rowptr[b * RP + t + 1] = scan[t];
            curs[t] = scan[t] - cnt;                   // exclusive prefix
            dinv[b * NN + t] = cnt > 0 ? rsqrtf((float)cnt) : 0.f;
        }
        if (t == 0) rowptr[b * RP] = 0;
        __syncthreads();
#pragma unroll
        for (int q = 0; q < 17; ++q) {
            if (cc[q] >= 0) {
                int slot = atomicAdd(&curs[cc[q]], 1); // LDS atomic
                csr_row[b * ET + slot] = rr[q];
            }
        }
        return;
    }
    // ---------------- weight prep ----------------
    int idx = (blockIdx.x - BB) * 1024 + t;
    if (idx < NSEG) {
        int lane = idx & 63, tc = idx >> 6;
        int ct = tc & 7, ks = tc >> 3;
        int tt = ks < 10 ? 0 : ks < 14 ? 1 : ks < 21 ? 2 : 3;
        int k0 = tt == 0 ? 0 : tt == 1 ? 10 : tt == 2 ? 14 : 21;
        const int Ktab[4] = {300, 100, 200, 200};
        const int Koff[4] = {0, 300, 400, 600};
        int ksl = ks - k0;
        f16x8 ph, pl;
#pragma unroll
        for (int j = 0; j < 8; ++j) {
            int k = ksl * 32 + (lane >> 4) * 8 + j;
            int c = ct * 16 + (lane & 15);
            float v = (k < Ktab[tt]) ? W[(size_t)(Koff[tt] + k) * CC + c] : 0.f;
            f16 hi = (f16)v;
            ph[j] = hi; pl[j] = (f16)(v - (float)hi);
        }
        *(f16x8*)(BWh + (size_t)idx * 8) = ph;
        *(f16x8*)(BWl + (size_t)idx * 8) = pl;
    } else if (idx < NSEG + NGAT) {
        int i2 = idx - NSEG;
        int lane = i2 & 63, tc = i2 >> 6;
        int ct = tc & 7; tc >>= 3;
        int ks = tc & 3, li = tc >> 2;
        const float* Wl = gat_W + (size_t)li * CC * CC;
        f16x8 ph, pl;
#pragma unroll
        for (int j = 0; j < 8; ++j) {
            int k = ks * 32 + (lane >> 4) * 8 + j;
            int c = ct * 16 + (lane & 15);
            float v = Wl[k * CC + c];
            f16 hi = (f16)v;
            ph[j] = hi; pl[j] = (f16)(v - (float)hi);
        }
        *(f16x8*)(BGh + (size_t)i2 * 8) = ph;
        *(f16x8*)(BGl + (size_t)i2 * 8) = pl;
    } else if (idx < NPREP) {
        int i2 = idx - NSEG - NGAT;
        int i = i2 >> 7, k = i2 & 127;
        const float* Wl = gat_W + (size_t)i * CC * CC;
        float s = 0.f, d = 0.f;
#pragma unroll 4
        for (int c = 0; c < CC; ++c) {
            float w = Wl[k * CC + c];
            s = fmaf(w, a_s[i * CC + c], s);
            d = fmaf(w, a_d[i * CC + c], d);
        }
        wsv[i * CC + k] = s; wdv[i * CC + k] = d;
    }
}

// ---- table-projection GEMM: P[t] = table[t] @ W_in[Koff:Koff+K]  (f32 out) ----
__global__ __launch_bounds__(256) void k_proj(
    const float* __restrict__ poi, const float* __restrict__ cat,
    const float* __restrict__ lat, const float* __restrict__ lon,
    const f16* __restrict__ Bh, const f16* __restrict__ Bl,
    float* __restrict__ P) {
    int bid = blockIdx.x;
    int t, r0;
    if (bid < 160)      { t = 0; r0 = bid * 32; }
    else if (bid < 173) { t = 1; r0 = (bid - 160) * 32; }
    else if (bid < 396) { t = 2; r0 = (bid - 173) * 32; }
    else                { t = 3; r0 = (bid - 396) * 32; }
    const int Ktab[4] = {300, 100, 200, 200};
    const int Rtab[4] = {5099, 400, 7128, 6394};
    const int Rofs[4] = {0, 5099, 5499, 12627};
    const int Kst[4]  = {10, 4, 7, 7};
    const int Bks0[4] = {0, 10, 14, 21};
    const float* tab = t == 0 ? poi : t == 1 ? cat : t == 2 ? lat : lon;
    int K = Ktab[t], R = Rtab[t], nks = Kst[t], bks = Bks0[t];
    int lane = threadIdx.x & 63, w = threadIdx.x >> 6;
    int ct0 = w * 2;
    f32x4 acc[2][2];
#pragma unroll
    for (int rt = 0; rt < 2; ++rt)
#pragma unroll
        for (int c = 0; c < 2; ++c) acc[rt][c] = (f32x4){0.f, 0.f, 0.f, 0.f};

    for (int ks = 0; ks < nks; ++ks) {
        int kbase = ks * 32 + (lane >> 4) * 8;
        f16x8 ah[2], al[2];
#pragma unroll
        for (int rt = 0; rt < 2; ++rt) {
            int row = r0 + rt * 16 + (lane & 15);
            int rowc = row < R ? row : R - 1;
            const float* rp = tab + (size_t)rowc * K;
            float v[8];
            if (kbase + 8 <= K) {
                float4 x0 = ((const float4*)(rp + kbase))[0];
                float4 x1 = ((const float4*)(rp + kbase))[1];
                v[0] = x0.x; v[1] = x0.y; v[2] = x0.z; v[3] = x0.w;
                v[4] = x1.x; v[5] = x1.y; v[6] = x1.z; v[7] = x1.w;
            } else if (kbase >= K) {
#pragma unroll
                for (int m = 0; m < 8; ++m) v[m] = 0.f;
            } else {
#pragma unroll
                for (int m = 0; m < 8; ++m) v[m] = (kbase + m < K) ? rp[kbase + m] : 0.f;
            }
#pragma unroll
            for (int j = 0; j < 8; ++j) {
                f16 hi = (f16)v[j];
                ah[rt][j] = hi; al[rt][j] = (f16)(v[j] - (float)hi);
            }
        }
#pragma unroll
        for (int cti = 0; cti < 2; ++cti) {
            int ct = ct0 + cti;
            f16x8 bh = *(const f16x8*)(Bh + ((size_t)((bks + ks) * 8 + ct) * 64 + lane) * 8);
            f16x8 bl = *(const f16x8*)(Bl + ((size_t)((bks + ks) * 8 + ct) * 64 + lane) * 8);
#pragma unroll
            for (int rt = 0; rt < 2; ++rt) {
                acc[rt][cti] = __builtin_amdgcn_mfma_f32_16x16x32_f16(ah[rt], bh, acc[rt][cti], 0, 0, 0);
                acc[rt][cti] = __builtin_amdgcn_mfma_f32_16x16x32_f16(al[rt], bh, acc[rt][cti], 0, 0, 0);
                acc[rt][cti] = __builtin_amdgcn_mfma_f32_16x16x32_f16(ah[rt], bl, acc[rt][cti], 0, 0, 0);
            }
        }
    }
#pragma unroll
    for (int rt = 0; rt < 2; ++rt)
#pragma unroll
        for (int cti = 0; cti < 2; ++cti)
#pragma unroll
            for (int i = 0; i < 4; ++i) {
                int row = r0 + rt * 16 + (lane >> 4) * 4 + i;
                if (row < R) {
                    int col = (ct0 + cti) * 16 + (lane & 15);
                    P[(size_t)(Rofs[t] + row) * CC + col] = acc[rt][cti][i];
                }
            }
}

// ---- per-node assembly: bufB[g] = P_poi[f0] + P_cat[f1] + P_lat[f3] + P_lon[f4] ----
__global__ __launch_bounds__(256) void k_assemble(
    const int* __restrict__ feature, const float* __restrict__ P,
    f16* __restrict__ out) {
    int tid = xcd_swz(blockIdx.x, gridDim.x) * 256 + threadIdx.x;
    int g = tid >> 4, c8 = (tid & 15) * 8;
    const int* f = feature + (size_t)g * 5;
    const float4* p0 = (const float4*)(P + (size_t)f[0] * CC + c8);
    const float4* p1 = (const float4*)(P + (size_t)(5099 + f[1]) * CC + c8);
    const float4* p2 = (const float4*)(P + (size_t)(5499 + f[3]) * CC + c8);
    const float4* p3 = (const float4*)(P + (size_t)(12627 + f[4]) * CC + c8);
    float4 a0 = p0[0], a1 = p0[1];
    float4 b0 = p1[0], b1 = p1[1];
    float4 c0 = p2[0], c1 = p2[1];
    float4 d0 = p3[0], d1 = p3[1];
    f16x8 r;
    r[0] = (f16)(a0.x + b0.x + c0.x + d0.x);
    r[1] = (f16)(a0.y + b0.y + c0.y + d0.y);
    r[2] = (f16)(a0.z + b0.z + c0.z + d0.z);
    r[3] = (f16)(a0.w + b0.w + c0.w + d0.w);
    r[4] = (f16)(a1.x + b1.x + c1.x + d1.x);
    r[5] = (f16)(a1.y + b1.y + c1.y + d1.y);
    r[6] = (f16)(a1.z + b1.z + c1.z + d1.z);
    r[7] = (f16)(a1.w + b1.w + c1.w + d1.w);
    *(f16x8*)(out + (size_t)g * CC + c8) = r;
}

// ---- GAT gemm, 32-row tile; f16 input (exact A, 2-term MFMA); f16 Hp out ----
__global__ __launch_bounds__(256) void k_gat_gemm(
    const f16* __restrict__ hin, const f16* __restrict__ Bh, const f16* __restrict__ Bl,
    const float* __restrict__ wsv, const float* __restrict__ wdv,
    f16* __restrict__ Hp, float* __restrict__ asrc, float* __restrict__ adst) {
    __shared__ __align__(16) f16 Ah[32 * 128];
    __shared__ float reds[256], redd[256];
    int t = threadIdx.x;
    int g0 = xcd_swz(blockIdx.x, gridDim.x) * 32;
    int lane = t & 63, w = t >> 6;
    int sr = t >> 3, skb = (t & 7) * 16;
    const f16x8* hrow = (const f16x8*)(hin + (size_t)(g0 + sr) * CC + skb);
    f16x8 hv0 = hrow[0], hv1 = hrow[1];
    float ps = 0.f, pd = 0.f;
#pragma unroll
    for (int m = 0; m < 8; ++m) {
        ps = fmaf((float)hv0[m], wsv[skb + m], ps);
        pd = fmaf((float)hv0[m], wdv[skb + m], pd);
        ps = fmaf((float)hv1[m], wsv[skb + 8 + m], ps);
        pd = fmaf((float)hv1[m], wdv[skb + 8 + m], pd);
    }
    {
        int kg0 = (t & 7) * 2;
        int ad0 = sr * 128 + ((kg0 ^ (sr & 7)) << 3);
        int ad1 = sr * 128 + (((kg0 + 1) ^ (sr & 7)) << 3);
        *(f16x8*)&Ah[ad0] = hv0;
        *(f16x8*)&Ah[ad1] = hv1;
    }
    reds[t] = ps; redd[t] = pd;
    __syncthreads();
    if (t < 32) {
        float s = 0.f, d = 0.f;
#pragma unroll
        for (int q = 0; q < 8; ++q) { s += reds[t * 8 + q]; d += redd[t * 8 + q]; }
        asrc[g0 + t] = s; adst[g0 + t] = d;
    }
    f32x4 acc[2][2];
#pragma unroll
    for (int rt = 0; rt < 2; ++rt)
#pragma unroll
        for (int c = 0; c < 2; ++c) acc[rt][c] = (f32x4){0.f, 0.f, 0.f, 0.f};
    int ct0 = w * 2;
#pragma unroll
    for (int ks = 0; ks < 4; ++ks) {
        f16x8 ahf[2];
#pragma unroll
        for (int rt = 0; rt < 2; ++rt) {
            int r = rt * 16 + (lane & 15);
            int kg = (lane >> 4) + ks * 4;
            int ad = r * 128 + ((kg ^ (r & 7)) << 3);
            ahf[rt] = *(const f16x8*)&Ah[ad];
        }
#pragma unroll
        for (int cti = 0; cti < 2; ++cti) {
            int ct = ct0 + cti;
            f16x8 bh = *(const f16x8*)(Bh + ((size_t)(ks * 8 + ct) * 64 + lane) * 8);
            f16x8 bl = *(const f16x8*)(Bl + ((size_t)(ks * 8 + ct) * 64 + lane) * 8);
#pragma unroll
            for (int rt = 0; rt < 2; ++rt) {
                acc[rt][cti] = __builtin_amdgcn_mfma_f32_16x16x32_f16(ahf[rt], bh, acc[rt][cti], 0, 0, 0);
                acc[rt][cti] = __builtin_amdgcn_mfma_f32_16x16x32_f16(ahf[rt], bl, acc[rt][cti], 0, 0, 0);
            }
        }
    }
#pragma unroll
    for (int rt = 0; rt < 2; ++rt)
#pragma unroll
        for (int cti = 0; cti < 2; ++cti)
#pragma unroll
            for (int i = 0; i < 4; ++i) {
                int row = g0 + rt * 16 + (lane >> 4) * 4 + i;
                int col = (ct0 + cti) * 16 + (lane & 15);
                Hp[(size_t)row * CC + col] = (f16)acc[rt][cti][i];
            }
}

// ---- unified aggregate kernel: 2 nodes per wave (32-lane half per node) ----
// MODE 0: GAT, out = lrelu01(t)+t. MODE 1: GAT, out = lrelu01(t).
// MODE 2: GCN, out = lrelu01(t). MODE 3: GAT plain, write only pscal = out.Wout.
template <int MODE>
__global__ __launch_bounds__(256) void k_agg(
    const f16* __restrict__ Hp, const float* __restrict__ aux,
    const float* __restrict__ adst, const int* __restrict__ rowptr,
    const int* __restrict__ csr_row, const float* __restrict__ bias,
    f16* __restrict__ out, const float* __restrict__ Wout, float* __restrict__ pscal) {
    __shared__ float2 pr[4][2][DFAST];
    int wid = threadIdx.x >> 6, lane = threadIdx.x & 63;
    int half = lane >> 5, hl = lane & 31;
    int g = xcd_swz(blockIdx.x, gridDim.x) * 8 + wid * 2 + half;
    int b = g / NN, v = g - b * NN;
    int bN = b * NN, bE = b * ET;
    int s0 = rowptr[b * RP + v], s1 = rowptr[b * RP + v + 1];
    int deg = s1 - s0;

    if (deg <= DFAST) {
        int degp = (deg + 7) & ~7;                 // pad to multiple of 8 (<=64)
        float inv = 1.f;
        // ---- phase 1: single pass, e in registers, half-wave reductions ----
        int r0 = 0, r1 = 0;
        float w0, w1;
        if (MODE == 2) {
            float dv = aux[g];
            w0 = w1 = 0.f;
            if (hl < deg)      { r0 = csr_row[bE + s0 + hl];      w0 = aux[bN + r0] * dv; }
            if (hl + 32 < deg) { r1 = csr_row[bE + s0 + hl + 32]; w1 = aux[bN + r1] * dv; }
        } else {
            float adv = adst[g];
            float e0 = -3.0e38f, e1 = -3.0e38f;
            if (hl < deg)      { r0 = csr_row[bE + s0 + hl];      e0 = lrelu2(aux[bN + r0] + adv); }
            if (hl + 32 < deg) { r1 = csr_row[bE + s0 + hl + 32]; e1 = lrelu2(aux[bN + r1] + adv); }
            float m = hmax(fmaxf(e0, e1));
            w0 = __expf(e0 - m);                    // inactive lanes: exp(-inf)=0
            w1 = __expf(e1 - m);
            float ss = hsum(w0 + w1);
            inv = 1.f / (ss + 1e-16f);              // applied once at the end
        }
        if (hl < degp)      pr[wid][half][hl]      = make_float2(w0, __int_as_float(r0));
        if (hl + 32 < degp) pr[wid][half][hl + 32] = make_float2(w1, __int_as_float(r1));
        // DS pipe is in-order per wave: phase-2 reads see this wave's writes.
        // ---- phase 2: branch-free; 4 chains x 2 edges in flight per half ----
        int eh = hl >> 4, ql = hl & 15;
        const f16* Hb = Hp + (size_t)bN * CC;
        float acc0[8], acc1[8], acc2[8], acc3[8];
#pragma unroll
        for (int j = 0; j < 8; ++j) { acc0[j] = 0.f; acc1[j] = 0.f; acc2[j] = 0.f; acc3[j] = 0.f; }
        for (int jj = 0; jj < degp; jj += 8) {
            float2 p0 = pr[wid][half][jj + eh];
            float2 p1 = pr[wid][half][jj + 2 + eh];
            float2 p2 = pr[wid][half][jj + 4 + eh];
            float2 p3 = pr[wid][half][jj + 6 + eh];
            f16x8 h0 = *(const f16x8*)(Hb + (size_t)__float_as_int(p0.y) * CC + ql * 8);
            f16x8 h1 = *(const f16x8*)(Hb + (size_t)__float_as_int(p1.y) * CC + ql * 8);
            f16x8 h2 = *(const f16x8*)(Hb + (size_t)__float_as_int(p2.y) * CC + ql * 8);
            f16x8 h3 = *(const f16x8*)(Hb + (size_t)__float_as_int(p3.y) * CC + ql * 8);
#pragma unroll
            for (int j = 0; j < 8; ++j) {
                acc0[j] = fmaf((float)h0[j], p0.x, acc0[j]);
                acc1[j] = fmaf((float)h1[j], p1.x, acc1[j]);
                acc2[j] = fmaf((float)h2[j], p2.x, acc2[j]);
                acc3[j] = fmaf((float)h3[j], p3.x, acc3[j]);
            }
        }
        float a0[8];
#pragma unroll
        for (int j = 0; j < 8; ++j) {
            float x = acc0[j] + acc1[j] + acc2[j] + acc3[j];
            x += __shfl_xor(x, 16);                 // combine eh=0/1 within the half
            a0[j] = x;
        }
        if (eh == 0) {
            float sc = (MODE == 2) ? 1.f : inv;
            float4 bb0 = ((const float4*)bias)[ql * 2];
            float4 bb1 = ((const float4*)bias)[ql * 2 + 1];
            float tv[8];
            tv[0] = a0[0] * sc + bb0.x; tv[1] = a0[1] * sc + bb0.y;
            tv[2] = a0[2] * sc + bb0.z; tv[3] = a0[3] * sc + bb0.w;
            tv[4] = a0[4] * sc + bb1.x; tv[5] = a0[5] * sc + bb1.y;
            tv[6] = a0[6] * sc + bb1.z; tv[7] = a0[7] * sc + bb1.w;
            float ov[8];
#pragma unroll
            for (int j = 0; j < 8; ++j) {
                float l = lrelu01(tv[j]);
                ov[j] = (MODE == 0) ? l + tv[j] : l;
            }
            if (MODE == 3) {
                // fused out_dot: pscal[g] = ov . Wout
                float4 w0v = ((const float4*)Wout)[ql * 2];
                float4 w1v = ((const float4*)Wout)[ql * 2 + 1];
                float p = ov[0] * w0v.x + ov[1] * w0v.y + ov[2] * w0v.z + ov[3] * w0v.w
                        + ov[4] * w1v.x + ov[5] * w1v.y + ov[6] * w1v.z + ov[7] * w1v.w;
#pragma unroll
                for (int o = 8; o > 0; o >>= 1) p += __shfl_xor(p, o);
                if (ql == 0) pscal[g] = p;
            } else {
                f16x8 r;
#pragma unroll
                for (int j = 0; j < 8; ++j) r[j] = (f16)ov[j];
                *(f16x8*)(out + (size_t)g * CC + ql * 8) = r;
            }
        }
        return;
    }
    // ---- fallback deg > DFAST: half-wave (32 lanes, 4 ch/lane); ~never taken ----
    {
        float wsc0 = 0.f;
        float m = 0.f, inv = 1.f, adv = 0.f;
        if (MODE != 2) {
            adv = adst[g];
            m = -3.0e38f;
            for (int j = s0 + hl; j < s1; j += 32)
                m = fmaxf(m, lrelu2(aux[bN + csr_row[bE + j]] + adv));
            m = hmax(m);
            float ssum = 0.f;
            for (int j = s0 + hl; j < s1; j += 32)
                ssum += __expf(lrelu2(aux[bN + csr_row[bE + j]] + adv) - m);
            ssum = hsum(ssum);
            inv = 1.f / (ssum + 1e-16f);
        } else {
            wsc0 = aux[g];
        }
        float x0 = 0.f, x1 = 0.f, x2 = 0.f, x3 = 0.f;
        for (int j = s0; j < s1; ++j) {
            int r = csr_row[bE + j];
            float wj = (MODE == 2) ? aux[bN + r]
                                   : __expf(lrelu2(aux[bN + r] + adv) - m) * inv;
            f16x4 h = *(const f16x4*)(Hp + (size_t)(bN + r) * CC + hl * 4);
            x0 = fmaf(wj, (float)h[0], x0);
            x1 = fmaf(wj, (float)h[1], x1);
            x2 = fmaf(wj, (float)h[2], x2);
            x3 = fmaf(wj, (float)h[3], x3);
        }
        if (MODE == 2) { x0 *= wsc0; x1 *= wsc0; x2 *= wsc0; x3 *= wsc0; }
        float4 bb = ((const float4*)bias)[hl];
        float t0 = x0 + bb.x, t1 = x1 + bb.y, t2 = x2 + bb.z, t3 = x3 + bb.w;
        float l0 = lrelu01(t0), l1 = lrelu01(t1), l2 = lrelu01(t2), l3 = lrelu01(t3);
        float o0 = (MODE == 0) ? l0 + t0 : l0;
        float o1 = (MODE == 0) ? l1 + t1 : l1;
        float o2 = (MODE == 0) ? l2 + t2 : l2;
        float o3 = (MODE == 0) ? l3 + t3 : l3;
        if (MODE == 3) {
            float4 w4 = ((const float4*)Wout)[hl];
            float p = o0 * w4.x + o1 * w4.y + o2 * w4.z + o3 * w4.w;
            p = hsum(p);
            if (hl == 0) pscal[g] = p;
        } else {
            f16x4 r;
            r[0] = (f16)o0; r[1] = (f16)o1; r[2] = (f16)o2; r[3] = (f16)o3;
            *(f16x4*)(out + (size_t)g * CC + hl * 4) = r;
        }
    }
}

__global__ __launch_bounds__(256) void k_out_agg(
    const float* __restrict__ p, const float* __restrict__ dinv,
    const int* __restrict__ rowptr, const int* __restrict__ csr_row,
    const float* __restrict__ bout, float* __restrict__ gv) {
    int wid = threadIdx.x >> 6, lane = threadIdx.x & 63;
    int g = xcd_swz(blockIdx.x, gridDim.x) * 4 + wid;
    int b = g / NN, v = g - b * NN;
    int s0 = rowptr[b * RP + v], s1 = rowptr[b * RP + v + 1];
    float acc = 0.f;
    for (int j = s0 + lane; j < s1; j += 64) {
        int r = csr_row[b * ET + j];
        acc += dinv[b * NN + r] * p[b * NN + r];
    }
    acc = wsum(acc);
    if (lane == 0) gv[g] = lrelu01(acc * dinv[g] + bout[0]);
}

__global__ __launch_bounds__(128) void k_fc(
    const float* __restrict__ gv, const float* __restrict__ W1,
    const float* __restrict__ b1, const float* __restrict__ W2,
    const float* __restrict__ b2, float* __restrict__ outp) {
    __shared__ float gs[NN];
    __shared__ float s1[CC];
    int b = blockIdx.x, tx = threadIdx.x;
    for (int v = tx; v < NN; v += 128) gs[v] = gv[b * NN + v];
    __syncthreads();
    float acc = 0.f;
    for (int v = 0; v < NN; ++v) acc = fmaf(gs[v], W1[v * CC + tx], acc);
    float t = lrelu01(acc + b1[tx]);
    s1[tx] = t;
    __syncthreads();
    float acc2 = 0.f;
#pragma unroll
    for (int k = 0; k < CC; ++k) acc2 = fmaf(s1[k], W2[k * CC + tx], acc2);
    outp[b * CC + tx] = acc2 + b2[tx];
}

extern "C" void kernel_launch(void* const* d_in, const int* in_sizes, int n_in,
                              void* d_out, int out_size, void* d_ws, size_t ws_size,
                              hipStream_t stream) {
    const int*   feature  = (const int*)d_in[0];
    const int*   edges    = (const int*)d_in[1];
    const float* poi      = (const float*)d_in[3];
    const float* cat      = (const float*)d_in[4];
    const float* lat      = (const float*)d_in[5];
    const float* lon      = (const float*)d_in[6];
    const float* W_in     = (const float*)d_in[7];
    const float* b_in     = (const float*)d_in[8];
    const float* gat_W    = (const float*)d_in[9];
    const float* gat_asrc = (const float*)d_in[10];
    const float* gat_adst = (const float*)d_in[11];
    const float* gat_b    = (const float*)d_in[12];
    const float* W_out    = (const float*)d_in[13];
    const float* b_out    = (const float*)d_in[14];
    const float* W_fc1    = (const float*)d_in[15];
    const float* b_fc1    = (const float*)d_in[16];
    const float* W_fc2    = (const float*)d_in[17];
    const float* b_fc2    = (const float*)d_in[18];
    float* outp = (float*)d_out;

    char* ws = (char*)d_ws;
    size_t off = 0;
    auto take = [&](size_t bytes) -> char* {
        char* pp = ws + off;
        off = (off + bytes + 255) & ~(size_t)255;
        return pp;
    };
    int*   csr    = (int*)take((size_t)BB * ET * 4);
    int*   rowptr = (int*)take((size_t)BB * RP * 4);
    float* dinv   = (float*)take((size_t)NBt * 4);
    float* asrc   = (float*)take((size_t)NBt * 4);
    float* adst   = (float*)take((size_t)NBt * 4);
    float* pscal  = (float*)take((size_t)NBt * 4);
    float* gvec   = (float*)take((size_t)NBt * 4);
    f16*   bufA   = (f16*)take((size_t)NBt * CC * 2);       // f16 node features
    f16*   bufB   = (f16*)take((size_t)NBt * CC * 2);       // f16 node features
    float* P      = (float*)take((size_t)PROJ_ROWS * CC * 4); // table projections
    f16*   BWh    = (f16*)take((size_t)KSP * 8 * 64 * 8 * 2);
    f16*   BWl    = (f16*)take((size_t)KSP * 8 * 64 * 8 * 2);
    f16*   BGh    = (f16*)take((size_t)3 * 4 * 8 * 64 * 8 * 2);
    f16*   BGl    = (f16*)take((size_t)3 * 4 * 8 * 64 * 8 * 2);
    float* wsv    = (float*)take((size_t)3 * CC * 4);
    float* wdv    = (float*)take((size_t)3 * CC * 4);

    // merged CSR build + weight prep: blocks [0,BB) build, [BB, BB+21) prep
    const int prep_blocks = (NPREP + 1023) / 1024;
    k_build_prep<<<BB + prep_blocks, 1024, 0, stream>>>(
        edges, rowptr, csr, dinv,
        W_in, gat_W, gat_asrc, gat_adst, BWh, BWl, BGh, BGl, wsv, wdv);

    k_proj<<<596, 256, 0, stream>>>(poi, cat, lat, lon, BWh, BWl, P);
    k_assemble<<<NBt * 16 / 256, 256, 0, stream>>>(feature, P, bufB);
    k_agg<2><<<NBt / 8, 256, 0, stream>>>(bufB, dinv, nullptr, rowptr, csr, b_in,
                                          bufA, nullptr, nullptr);

    for (int i = 0; i < 3; ++i) {
        const f16* bh = BGh + (size_t)i * 4 * 8 * 64 * 8;
        const f16* bl = BGl + (size_t)i * 4 * 8 * 64 * 8;
        const float* ws_i = wsv + (size_t)i * CC;
        const float* wd_i = wdv + (size_t)i * CC;
        const float* gb = gat_b + (size_t)i * CC;
        k_gat_gemm<<<NBt / 32, 256, 0, stream>>>(bufA, bh, bl, ws_i, wd_i, bufB, asrc, adst);
        k_agg<0><<<NBt / 8, 256, 0, stream>>>(bufB, asrc, adst, rowptr, csr, gb,
                                              bufA, nullptr, nullptr);
        k_gat_gemm<<<NBt / 32, 256, 0, stream>>>(bufA, bh, bl, ws_i, wd_i, bufB, asrc, adst);
        if (i < 2) {
            k_agg<1><<<NBt / 8, 256, 0, stream>>>(bufB, asrc, adst, rowptr, csr, gb,
                                                  bufA, nullptr, nullptr);
        } else {
            // last agg: fuse the W_out per-node dot, write pscal only
            k_agg<3><<<NBt / 8, 256, 0, stream>>>(bufB, asrc, adst, rowptr, csr, gb,
                                                  bufA, W_out, pscal);
        }
    }

    k_out_agg<<<NBt / 4, 256, 0, stream>>>(pscal, dinv, rowptr, csr, b_out, gvec);
    k_fc<<<BB, 128, 0, stream>>>(gvec, W_fc1, b_fc1, W_fc2, b_fc2, outp);
}

// Round 16
// 290.124 us; speedup vs baseline: 1.1058x; 1.0036x over previous
//
#include <hip/hip_runtime.h>

// UserGraphNet: B=64 graphs, n=714 nodes, E=16384 edges (+n self loops), C=128.
// Round 15: agg phase-2 software-pipelined 2-deep (issue next iteration's pr reads
// + 4 gathers before current iteration's fmas -> 8 gathers in flight, latency of
// iter j+1 hidden under fmas of iter j). Otherwise identical to round 14:
// split structure, 2-node/wave register softmax aggs, f16 features end-to-end,
// 2-term MFMA GEMMs, merged build+prep, table-projection embed, XCD swizzle.

#define BB 64
#define NN 714
#define EE 16384
#define ET (EE + NN)          // 17098 edges incl self loops
#define NBt (BB * NN)         // 45696 total nodes
#define CC 128
#define RP (NN + 1)           // rowptr entries per graph
#define DFAST 64              // max degree on the 2-node/wave fast path (deg~24)
#define KSP 28                // total padded k-steps across 4 table projections
#define PROJ_ROWS 19021       // 5099 + 400 + 7128 + 6394

typedef _Float16 f16;
typedef __attribute__((ext_vector_type(8))) _Float16 f16x8;
typedef __attribute__((ext_vector_type(4))) _Float16 f16x4;
typedef __attribute__((ext_vector_type(4))) float f32x4;

__device__ __forceinline__ float lrelu01(float x) { return x > 0.f ? x : 0.01f * x; }
__device__ __forceinline__ float lrelu2(float x)  { return x > 0.f ? x : 0.2f  * x; }

__device__ __forceinline__ float wsum(float x) {
#pragma unroll
    for (int o = 32; o > 0; o >>= 1) x += __shfl_xor(x, o);
    return x;
}
__device__ __forceinline__ float hsum(float x) {
#pragma unroll
    for (int o = 16; o > 0; o >>= 1) x += __shfl_xor(x, o);
    return x;
}
__device__ __forceinline__ float hmax(float x) {
#pragma unroll
    for (int o = 16; o > 0; o >>= 1) x = fmaxf(x, __shfl_xor(x, o));
    return x;
}

// Bijective XCD swizzle (m204)
__device__ __forceinline__ int xcd_swz(int bid, int nwg) {
    int q = nwg >> 3, r = nwg & 7;
    int x = bid & 7, l = bid >> 3;
    int base = (x < r) ? x * (q + 1) : r * (q + 1) + (x - r) * q;
    return base + l;
}

// ---- merged CSR build (blocks 0..BB-1) + weight prep (blocks BB..) ----
#define NSEG (KSP * 8 * 64)
#define NGAT (3 * 4 * 8 * 64)
#define NPREP (NSEG + NGAT + 3 * CC)
__global__ __launch_bounds__(1024) void k_build_prep(
    const int* __restrict__ edges, int* __restrict__ rowptr,
    int* __restrict__ csr_row, float* __restrict__ dinv,
    const float* __restrict__ W, const float* __restrict__ gat_W,
    const float* __restrict__ a_s, const float* __restrict__ a_d,
    f16* __restrict__ BWh, f16* __restrict__ BWl,
    f16* __restrict__ BGh, f16* __restrict__ BGl,
    float* __restrict__ wsv, float* __restrict__ wdv) {
    __shared__ int degs[NN];
    __shared__ int scan[1024];
    __shared__ int curs[NN];
    int t = threadIdx.x;
    if (blockIdx.x < BB) {
        // ---------------- CSR build ----------------
        int b = blockIdx.x;
        if (t < NN) degs[t] = 0;
        __syncthreads();
        int rr[17], cc[17];
#pragma unroll
        for (int q = 0; q < 17; ++q) {
            int e = q * 1024 + t;
            int r = -1, c = -1;
            if (e < ET) {
                if (e < EE) { r = edges[b * 2 * EE + e]; c = edges[b * 2 * EE + EE + e]; }
                else        { r = c = e - EE; }
                atomicAdd(&degs[c], 1);
            }
            rr[q] = r; cc[q] = c;
        }
        __syncthreads();
        int cnt = (t < NN) ? degs[t] : 0;
        scan[t] = cnt;
        __syncthreads();
        for (int off = 1; off < 1024; off <<= 1) {
            int val = (t >= off) ? scan[t - off] : 0;
            __syncthreads();
            scan[t] += val;
            __syncthreads();
        }
        if (t < NN) {
            rowptr[b * RP + t + 1] = scan[t];
            curs[t] = scan[t] - cnt;                   // exclusive prefix
            dinv[b * NN + t] = cnt > 0 ? rsqrtf((float)cnt) : 0.f;
        }
        if (t == 0) rowptr[b * RP] = 0;
        __syncthreads();
#pragma unroll
        for (int q = 0; q < 17; ++q) {
            if (cc[q] >= 0) {
                int slot = atomicAdd(&curs[cc[q]], 1); // LDS atomic
                csr_row[b * ET + slot] = rr[q];
            }
        }
        return;
    }
    // ---------------- weight prep ----------------
    int idx = (blockIdx.x - BB) * 1024 + t;
    if (idx < NSEG) {
        int lane = idx & 63, tc = idx >> 6;
        int ct = tc & 7, ks = tc >> 3;
        int tt = ks < 10 ? 0 : ks < 14 ? 1 : ks < 21 ? 2 : 3;
        int k0 = tt == 0 ? 0 : tt == 1 ? 10 : tt == 2 ? 14 : 21;
        const int Ktab[4] = {300, 100, 200, 200};
        const int Koff[4] = {0, 300, 400, 600};
        int ksl = ks - k0;
        f16x8 ph, pl;
#pragma unroll
        for (int j = 0; j < 8; ++j) {
            int k = ksl * 32 + (lane >> 4) * 8 + j;
            int c = ct * 16 + (lane & 15);
            float v = (k < Ktab[tt]) ? W[(size_t)(Koff[tt] + k) * CC + c] : 0.f;
            f16 hi = (f16)v;
            ph[j] = hi; pl[j] = (f16)(v - (float)hi);
        }
        *(f16x8*)(BWh + (size_t)idx * 8) = ph;
        *(f16x8*)(BWl + (size_t)idx * 8) = pl;
    } else if (idx < NSEG + NGAT) {
        int i2 = idx - NSEG;
        int lane = i2 & 63, tc = i2 >> 6;
        int ct = tc & 7; tc >>= 3;
        int ks = tc & 3, li = tc >> 2;
        const float* Wl = gat_W + (size_t)li * CC * CC;
        f16x8 ph, pl;
#pragma unroll
        for (int j = 0; j < 8; ++j) {
            int k = ks * 32 + (lane >> 4) * 8 + j;
            int c = ct * 16 + (lane & 15);
            float v = Wl[k * CC + c];
            f16 hi = (f16)v;
            ph[j] = hi; pl[j] = (f16)(v - (float)hi);
        }
        *(f16x8*)(BGh + (size_t)i2 * 8) = ph;
        *(f16x8*)(BGl + (size_t)i2 * 8) = pl;
    } else if (idx < NPREP) {
        int i2 = idx - NSEG - NGAT;
        int i = i2 >> 7, k = i2 & 127;
        const float* Wl = gat_W + (size_t)i * CC * CC;
        float s = 0.f, d = 0.f;
#pragma unroll 4
        for (int c = 0; c < CC; ++c) {
            float w = Wl[k * CC + c];
            s = fmaf(w, a_s[i * CC + c], s);
            d = fmaf(w, a_d[i * CC + c], d);
        }
        wsv[i * CC + k] = s; wdv[i * CC + k] = d;
    }
}

// ---- table-projection GEMM: P[t] = table[t] @ W_in[Koff:Koff+K]  (f32 out) ----
__global__ __launch_bounds__(256) void k_proj(
    const float* __restrict__ poi, const float* __restrict__ cat,
    const float* __restrict__ lat, const float* __restrict__ lon,
    const f16* __restrict__ Bh, const f16* __restrict__ Bl,
    float* __restrict__ P) {
    int bid = blockIdx.x;
    int t, r0;
    if (bid < 160)      { t = 0; r0 = bid * 32; }
    else if (bid < 173) { t = 1; r0 = (bid - 160) * 32; }
    else if (bid < 396) { t = 2; r0 = (bid - 173) * 32; }
    else                { t = 3; r0 = (bid - 396) * 32; }
    const int Ktab[4] = {300, 100, 200, 200};
    const int Rtab[4] = {5099, 400, 7128, 6394};
    const int Rofs[4] = {0, 5099, 5499, 12627};
    const int Kst[4]  = {10, 4, 7, 7};
    const int Bks0[4] = {0, 10, 14, 21};
    const float* tab = t == 0 ? poi : t == 1 ? cat : t == 2 ? lat : lon;
    int K = Ktab[t], R = Rtab[t], nks = Kst[t], bks = Bks0[t];
    int lane = threadIdx.x & 63, w = threadIdx.x >> 6;
    int ct0 = w * 2;
    f32x4 acc[2][2];
#pragma unroll
    for (int rt = 0; rt < 2; ++rt)
#pragma unroll
        for (int c = 0; c < 2; ++c) acc[rt][c] = (f32x4){0.f, 0.f, 0.f, 0.f};

    for (int ks = 0; ks < nks; ++ks) {
        int kbase = ks * 32 + (lane >> 4) * 8;
        f16x8 ah[2], al[2];
#pragma unroll
        for (int rt = 0; rt < 2; ++rt) {
            int row = r0 + rt * 16 + (lane & 15);
            int rowc = row < R ? row : R - 1;
            const float* rp = tab + (size_t)rowc * K;
            float v[8];
            if (kbase + 8 <= K) {
                float4 x0 = ((const float4*)(rp + kbase))[0];
                float4 x1 = ((const float4*)(rp + kbase))[1];
                v[0] = x0.x; v[1] = x0.y; v[2] = x0.z; v[3] = x0.w;
                v[4] = x1.x; v[5] = x1.y; v[6] = x1.z; v[7] = x1.w;
            } else if (kbase >= K) {
#pragma unroll
                for (int m = 0; m < 8; ++m) v[m] = 0.f;
            } else {
#pragma unroll
                for (int m = 0; m < 8; ++m) v[m] = (kbase + m < K) ? rp[kbase + m] : 0.f;
            }
#pragma unroll
            for (int j = 0; j < 8; ++j) {
                f16 hi = (f16)v[j];
                ah[rt][j] = hi; al[rt][j] = (f16)(v[j] - (float)hi);
            }
        }
#pragma unroll
        for (int cti = 0; cti < 2; ++cti) {
            int ct = ct0 + cti;
            f16x8 bh = *(const f16x8*)(Bh + ((size_t)((bks + ks) * 8 + ct) * 64 + lane) * 8);
            f16x8 bl = *(const f16x8*)(Bl + ((size_t)((bks + ks) * 8 + ct) * 64 + lane) * 8);
#pragma unroll
            for (int rt = 0; rt < 2; ++rt) {
                acc[rt][cti] = __builtin_amdgcn_mfma_f32_16x16x32_f16(ah[rt], bh, acc[rt][cti], 0, 0, 0);
                acc[rt][cti] = __builtin_amdgcn_mfma_f32_16x16x32_f16(al[rt], bh, acc[rt][cti], 0, 0, 0);
                acc[rt][cti] = __builtin_amdgcn_mfma_f32_16x16x32_f16(ah[rt], bl, acc[rt][cti], 0, 0, 0);
            }
        }
    }
#pragma unroll
    for (int rt = 0; rt < 2; ++rt)
#pragma unroll
        for (int cti = 0; cti < 2; ++cti)
#pragma unroll
            for (int i = 0; i < 4; ++i) {
                int row = r0 + rt * 16 + (lane >> 4) * 4 + i;
                if (row < R) {
                    int col = (ct0 + cti) * 16 + (lane & 15);
                    P[(size_t)(Rofs[t] + row) * CC + col] = acc[rt][cti][i];
                }
            }
}

// ---- per-node assembly: bufB[g] = P_poi[f0] + P_cat[f1] + P_lat[f3] + P_lon[f4] ----
__global__ __launch_bounds__(256) void k_assemble(
    const int* __restrict__ feature, const float* __restrict__ P,
    f16* __restrict__ out) {
    int tid = xcd_swz(blockIdx.x, gridDim.x) * 256 + threadIdx.x;
    int g = tid >> 4, c8 = (tid & 15) * 8;
    const int* f = feature + (size_t)g * 5;
    const float4* p0 = (const float4*)(P + (size_t)f[0] * CC + c8);
    const float4* p1 = (const float4*)(P + (size_t)(5099 + f[1]) * CC + c8);
    const float4* p2 = (const float4*)(P + (size_t)(5499 + f[3]) * CC + c8);
    const float4* p3 = (const float4*)(P + (size_t)(12627 + f[4]) * CC + c8);
    float4 a0 = p0[0], a1 = p0[1];
    float4 b0 = p1[0], b1 = p1[1];
    float4 c0 = p2[0], c1 = p2[1];
    float4 d0 = p3[0], d1 = p3[1];
    f16x8 r;
    r[0] = (f16)(a0.x + b0.x + c0.x + d0.x);
    r[1] = (f16)(a0.y + b0.y + c0.y + d0.y);
    r[2] = (f16)(a0.z + b0.z + c0.z + d0.z);
    r[3] = (f16)(a0.w + b0.w + c0.w + d0.w);
    r[4] = (f16)(a1.x + b1.x + c1.x + d1.x);
    r[5] = (f16)(a1.y + b1.y + c1.y + d1.y);
    r[6] = (f16)(a1.z + b1.z + c1.z + d1.z);
    r[7] = (f16)(a1.w + b1.w + c1.w + d1.w);
    *(f16x8*)(out + (size_t)g * CC + c8) = r;
}

// ---- GAT gemm, 32-row tile; f16 input (exact A, 2-term MFMA); f16 Hp out ----
__global__ __launch_bounds__(256) void k_gat_gemm(
    const f16* __restrict__ hin, const f16* __restrict__ Bh, const f16* __restrict__ Bl,
    const float* __restrict__ wsv, const float* __restrict__ wdv,
    f16* __restrict__ Hp, float* __restrict__ asrc, float* __restrict__ adst) {
    __shared__ __align__(16) f16 Ah[32 * 128];
    __shared__ float reds[256], redd[256];
    int t = threadIdx.x;
    int g0 = xcd_swz(blockIdx.x, gridDim.x) * 32;
    int lane = t & 63, w = t >> 6;
    int sr = t >> 3, skb = (t & 7) * 16;
    const f16x8* hrow = (const f16x8*)(hin + (size_t)(g0 + sr) * CC + skb);
    f16x8 hv0 = hrow[0], hv1 = hrow[1];
    float ps = 0.f, pd = 0.f;
#pragma unroll
    for (int m = 0; m < 8; ++m) {
        ps = fmaf((float)hv0[m], wsv[skb + m], ps);
        pd = fmaf((float)hv0[m], wdv[skb + m], pd);
        ps = fmaf((float)hv1[m], wsv[skb + 8 + m], ps);
        pd = fmaf((float)hv1[m], wdv[skb + 8 + m], pd);
    }
    {
        int kg0 = (t & 7) * 2;
        int ad0 = sr * 128 + ((kg0 ^ (sr & 7)) << 3);
        int ad1 = sr * 128 + (((kg0 + 1) ^ (sr & 7)) << 3);
        *(f16x8*)&Ah[ad0] = hv0;
        *(f16x8*)&Ah[ad1] = hv1;
    }
    reds[t] = ps; redd[t] = pd;
    __syncthreads();
    if (t < 32) {
        float s = 0.f, d = 0.f;
#pragma unroll
        for (int q = 0; q < 8; ++q) { s += reds[t * 8 + q]; d += redd[t * 8 + q]; }
        asrc[g0 + t] = s; adst[g0 + t] = d;
    }
    f32x4 acc[2][2];
#pragma unroll
    for (int rt = 0; rt < 2; ++rt)
#pragma unroll
        for (int c = 0; c < 2; ++c) acc[rt][c] = (f32x4){0.f, 0.f, 0.f, 0.f};
    int ct0 = w * 2;
#pragma unroll
    for (int ks = 0; ks < 4; ++ks) {
        f16x8 ahf[2];
#pragma unroll
        for (int rt = 0; rt < 2; ++rt) {
            int r = rt * 16 + (lane & 15);
            int kg = (lane >> 4) + ks * 4;
            int ad = r * 128 + ((kg ^ (r & 7)) << 3);
            ahf[rt] = *(const f16x8*)&Ah[ad];
        }
#pragma unroll
        for (int cti = 0; cti < 2; ++cti) {
            int ct = ct0 + cti;
            f16x8 bh = *(const f16x8*)(Bh + ((size_t)(ks * 8 + ct) * 64 + lane) * 8);
            f16x8 bl = *(const f16x8*)(Bl + ((size_t)(ks * 8 + ct) * 64 + lane) * 8);
#pragma unroll
            for (int rt = 0; rt < 2; ++rt) {
                acc[rt][cti] = __builtin_amdgcn_mfma_f32_16x16x32_f16(ahf[rt], bh, acc[rt][cti], 0, 0, 0);
                acc[rt][cti] = __builtin_amdgcn_mfma_f32_16x16x32_f16(ahf[rt], bl, acc[rt][cti], 0, 0, 0);
            }
        }
    }
#pragma unroll
    for (int rt = 0; rt < 2; ++rt)
#pragma unroll
        for (int cti = 0; cti < 2; ++cti)
#pragma unroll
            for (int i = 0; i < 4; ++i) {
                int row = g0 + rt * 16 + (lane >> 4) * 4 + i;
                int col = (ct0 + cti) * 16 + (lane & 15);
                Hp[(size_t)row * CC + col] = (f16)acc[rt][cti][i];
            }
}

// ---- unified aggregate kernel: 2 nodes per wave, phase-2 pipelined 2-deep ----
// MODE 0: GAT, out = lrelu01(t)+t. MODE 1: GAT, out = lrelu01(t).
// MODE 2: GCN, out = lrelu01(t). MODE 3: GAT plain, write only pscal = out.Wout.
template <int MODE>
__global__ __launch_bounds__(256) void k_agg(
    const f16* __restrict__ Hp, const float* __restrict__ aux,
    const float* __restrict__ adst, const int* __restrict__ rowptr,
    const int* __restrict__ csr_row, const float* __restrict__ bias,
    f16* __restrict__ out, const float* __restrict__ Wout, float* __restrict__ pscal) {
    __shared__ float2 pr[4][2][DFAST];
    int wid = threadIdx.x >> 6, lane = threadIdx.x & 63;
    int half = lane >> 5, hl = lane & 31;
    int g = xcd_swz(blockIdx.x, gridDim.x) * 8 + wid * 2 + half;
    int b = g / NN, v = g - b * NN;
    int bN = b * NN, bE = b * ET;
    int s0 = rowptr[b * RP + v], s1 = rowptr[b * RP + v + 1];
    int deg = s1 - s0;

    if (deg <= DFAST) {
        int degp = (deg + 7) & ~7;                 // pad to multiple of 8 (>=8)
        float inv = 1.f;
        // ---- phase 1: single pass, e in registers, half-wave reductions ----
        int r0 = 0, r1 = 0;
        float w0, w1;
        if (MODE == 2) {
            float dv = aux[g];
            w0 = w1 = 0.f;
            if (hl < deg)      { r0 = csr_row[bE + s0 + hl];      w0 = aux[bN + r0] * dv; }
            if (hl + 32 < deg) { r1 = csr_row[bE + s0 + hl + 32]; w1 = aux[bN + r1] * dv; }
        } else {
            float adv = adst[g];
            float e0 = -3.0e38f, e1 = -3.0e38f;
            if (hl < deg)      { r0 = csr_row[bE + s0 + hl];      e0 = lrelu2(aux[bN + r0] + adv); }
            if (hl + 32 < deg) { r1 = csr_row[bE + s0 + hl + 32]; e1 = lrelu2(aux[bN + r1] + adv); }
            float m = hmax(fmaxf(e0, e1));
            w0 = __expf(e0 - m);                    // inactive lanes: exp(-inf)=0
            w1 = __expf(e1 - m);
            float ss = hsum(w0 + w1);
            inv = 1.f / (ss + 1e-16f);              // applied once at the end
        }
        if (hl < degp)      pr[wid][half][hl]      = make_float2(w0, __int_as_float(r0));
        if (hl + 32 < degp) pr[wid][half][hl + 32] = make_float2(w1, __int_as_float(r1));
        // DS pipe is in-order per wave: phase-2 reads see this wave's writes.
        // ---- phase 2: 2-deep pipelined gather (8 loads in flight per half) ----
        int eh = hl >> 4, ql = hl & 15;
        const f16* Hb = Hp + (size_t)bN * CC;
        float acc0[8], acc1[8], acc2[8], acc3[8];
#pragma unroll
        for (int j = 0; j < 8; ++j) { acc0[j] = 0.f; acc1[j] = 0.f; acc2[j] = 0.f; acc3[j] = 0.f; }
        // prologue: iteration 0 (degp >= 8 always: self-loops => deg >= 1)
        float2 q0 = pr[wid][half][eh];
        float2 q1 = pr[wid][half][2 + eh];
        float2 q2 = pr[wid][half][4 + eh];
        float2 q3 = pr[wid][half][6 + eh];
        f16x8 g0 = *(const f16x8*)(Hb + (size_t)__float_as_int(q0.y) * CC + ql * 8);
        f16x8 g1 = *(const f16x8*)(Hb + (size_t)__float_as_int(q1.y) * CC + ql * 8);
        f16x8 g2 = *(const f16x8*)(Hb + (size_t)__float_as_int(q2.y) * CC + ql * 8);
        f16x8 g3 = *(const f16x8*)(Hb + (size_t)__float_as_int(q3.y) * CC + ql * 8);
        for (int jj = 8; jj < degp; jj += 8) {
            // issue next iteration's pr reads + gathers BEFORE consuming current
            float2 n0 = pr[wid][half][jj + eh];
            float2 n1 = pr[wid][half][jj + 2 + eh];
            float2 n2 = pr[wid][half][jj + 4 + eh];
            float2 n3 = pr[wid][half][jj + 6 + eh];
            f16x8 m0 = *(const f16x8*)(Hb + (size_t)__float_as_int(n0.y) * CC + ql * 8);
            f16x8 m1 = *(const f16x8*)(Hb + (size_t)__float_as_int(n1.y) * CC + ql * 8);
            f16x8 m2 = *(const f16x8*)(Hb + (size_t)__float_as_int(n2.y) * CC + ql * 8);
            f16x8 m3 = *(const f16x8*)(Hb + (size_t)__float_as_int(n3.y) * CC + ql * 8);
#pragma unroll
            for (int j = 0; j < 8; ++j) {
                acc0[j] = fmaf((float)g0[j], q0.x, acc0[j]);
                acc1[j] = fmaf((float)g1[j], q1.x, acc1[j]);
                acc2[j] = fmaf((float)g2[j], q2.x, acc2[j]);
                acc3[j] = fmaf((float)g3[j], q3.x, acc3[j]);
            }
            q0 = n0; q1 = n1; q2 = n2; q3 = n3;
            g0 = m0; g1 = m1; g2 = m2; g3 = m3;
        }
        // epilogue: consume last iteration
#pragma unroll
        for (int j = 0; j < 8; ++j) {
            acc0[j] = fmaf((float)g0[j], q0.x, acc0[j]);
            acc1[j] = fmaf((float)g1[j], q1.x, acc1[j]);
            acc2[j] = fmaf((float)g2[j], q2.x, acc2[j]);
            acc3[j] = fmaf((float)g3[j], q3.x, acc3[j]);
        }
        float a0[8];
#pragma unroll
        for (int j = 0; j < 8; ++j) {
            float x = acc0[j] + acc1[j] + acc2[j] + acc3[j];
            x += __shfl_xor(x, 16);                 // combine eh=0/1 within the half
            a0[j] = x;
        }
        if (eh == 0) {
            float sc = (MODE == 2) ? 1.f : inv;
            float4 bb0 = ((const float4*)bias)[ql * 2];
            float4 bb1 = ((const float4*)bias)[ql * 2 + 1];
            float tv[8];
            tv[0] = a0[0] * sc + bb0.x; tv[1] = a0[1] * sc + bb0.y;
            tv[2] = a0[2] * sc + bb0.z; tv[3] = a0[3] * sc + bb0.w;
            tv[4] = a0[4] * sc + bb1.x; tv[5] = a0[5] * sc + bb1.y;
            tv[6] = a0[6] * sc + bb1.z; tv[7] = a0[7] * sc + bb1.w;
            float ov[8];
#pragma unroll
            for (int j = 0; j < 8; ++j) {
                float l = lrelu01(tv[j]);
                ov[j] = (MODE == 0) ? l + tv[j] : l;
            }
            if (MODE == 3) {
                // fused out_dot: pscal[g] = ov . Wout
                float4 w0v = ((const float4*)Wout)[ql * 2];
                float4 w1v = ((const float4*)Wout)[ql * 2 + 1];
                float p = ov[0] * w0v.x + ov[1] * w0v.y + ov[2] * w0v.z + ov[3] * w0v.w
                        + ov[4] * w1v.x + ov[5] * w1v.y + ov[6] * w1v.z + ov[7] * w1v.w;
#pragma unroll
                for (int o = 8; o > 0; o >>= 1) p += __shfl_xor(p, o);
                if (ql == 0) pscal[g] = p;
            } else {
                f16x8 r;
#pragma unroll
                for (int j = 0; j < 8; ++j) r[j] = (f16)ov[j];
                *(f16x8*)(out + (size_t)g * CC + ql * 8) = r;
            }
        }
        return;
    }
    // ---- fallback deg > DFAST: half-wave (32 lanes, 4 ch/lane); ~never taken ----
    {
        float wsc0 = 0.f;
        float m = 0.f, inv = 1.f, adv = 0.f;
        if (MODE != 2) {
            adv = adst[g];
            m = -3.0e38f;
            for (int j = s0 + hl; j < s1; j += 32)
                m = fmaxf(m, lrelu2(aux[bN + csr_row[bE + j]] + adv));
            m = hmax(m);
            float ssum = 0.f;
            for (int j = s0 + hl; j < s1; j += 32)
                ssum += __expf(lrelu2(aux[bN + csr_row[bE + j]] + adv) - m);
            ssum = hsum(ssum);
            inv = 1.f / (ssum + 1e-16f);
        } else {
            wsc0 = aux[g];
        }
        float x0 = 0.f, x1 = 0.f, x2 = 0.f, x3 = 0.f;
        for (int j = s0; j < s1; ++j) {
            int r = csr_row[bE + j];
            float wj = (MODE == 2) ? aux[bN + r]
                                   : __expf(lrelu2(aux[bN + r] + adv) - m) * inv;
            f16x4 h = *(const f16x4*)(Hp + (size_t)(bN + r) * CC + hl * 4);
            x0 = fmaf(wj, (float)h[0], x0);
            x1 = fmaf(wj, (float)h[1], x1);
            x2 = fmaf(wj, (float)h[2], x2);
            x3 = fmaf(wj, (float)h[3], x3);
        }
        if (MODE == 2) { x0 *= wsc0; x1 *= wsc0; x2 *= wsc0; x3 *= wsc0; }
        float4 bb = ((const float4*)bias)[hl];
        float t0 = x0 + bb.x, t1 = x1 + bb.y, t2 = x2 + bb.z, t3 = x3 + bb.w;
        float l0 = lrelu01(t0), l1 = lrelu01(t1), l2 = lrelu01(t2), l3 = lrelu01(t3);
        float o0 = (MODE == 0) ? l0 + t0 : l0;
        float o1 = (MODE == 0) ? l1 + t1 : l1;
        float o2 = (MODE == 0) ? l2 + t2 : l2;
        float o3 = (MODE == 0) ? l3 + t3 : l3;
        if (MODE == 3) {
            float4 w4 = ((const float4*)Wout)[hl];
            float p = o0 * w4.x + o1 * w4.y + o2 * w4.z + o3 * w4.w;
            p = hsum(p);
            if (hl == 0) pscal[g] = p;
        } else {
            f16x4 r;
            r[0] = (f16)o0; r[1] = (f16)o1; r[2] = (f16)o2; r[3] = (f16)o3;
            *(f16x4*)(out + (size_t)g * CC + hl * 4) = r;
        }
    }
}

__global__ __launch_bounds__(256) void k_out_agg(
    const float* __restrict__ p, const float* __restrict__ dinv,
    const int* __restrict__ rowptr, const int* __restrict__ csr_row,
    const float* __restrict__ bout, float* __restrict__ gv) {
    int wid = threadIdx.x >> 6, lane = threadIdx.x & 63;
    int g = xcd_swz(blockIdx.x, gridDim.x) * 4 + wid;
    int b = g / NN, v = g - b * NN;
    int s0 = rowptr[b * RP + v], s1 = rowptr[b * RP + v + 1];
    float acc = 0.f;
    for (int j = s0 + lane; j < s1; j += 64) {
        int r = csr_row[b * ET + j];
        acc += dinv[b * NN + r] * p[b * NN + r];
    }
    acc = wsum(acc);
    if (lane == 0) gv[g] = lrelu01(acc * dinv[g] + bout[0]);
}

__global__ __launch_bounds__(128) void k_fc(
    const float* __restrict__ gv, const float* __restrict__ W1,
    const float* __restrict__ b1, const float* __restrict__ W2,
    const float* __restrict__ b2, float* __restrict__ outp) {
    __shared__ float gs[NN];
    __shared__ float s1[CC];
    int b = blockIdx.x, tx = threadIdx.x;
    for (int v = tx; v < NN; v += 128) gs[v] = gv[b * NN + v];
    __syncthreads();
    float acc = 0.f;
    for (int v = 0; v < NN; ++v) acc = fmaf(gs[v], W1[v * CC + tx], acc);
    float t = lrelu01(acc + b1[tx]);
    s1[tx] = t;
    __syncthreads();
    float acc2 = 0.f;
#pragma unroll
    for (int k = 0; k < CC; ++k) acc2 = fmaf(s1[k], W2[k * CC + tx], acc2);
    outp[b * CC + tx] = acc2 + b2[tx];
}

extern "C" void kernel_launch(void* const* d_in, const int* in_sizes, int n_in,
                              void* d_out, int out_size, void* d_ws, size_t ws_size,
                              hipStream_t stream) {
    const int*   feature  = (const int*)d_in[0];
    const int*   edges    = (const int*)d_in[1];
    const float* poi      = (const float*)d_in[3];
    const float* cat      = (const float*)d_in[4];
    const float* lat      = (const float*)d_in[5];
    const float* lon      = (const float*)d_in[6];
    const float* W_in     = (const float*)d_in[7];
    const float* b_in     = (const float*)d_in[8];
    const float* gat_W    = (const float*)d_in[9];
    const float* gat_asrc = (const float*)d_in[10];
    const float* gat_adst = (const float*)d_in[11];
    const float* gat_b    = (const float*)d_in[12];
    const float* W_out    = (const float*)d_in[13];
    const float* b_out    = (const float*)d_in[14];
    const float* W_fc1    = (const float*)d_in[15];
    const float* b_fc1    = (const float*)d_in[16];
    const float* W_fc2    = (const float*)d_in[17];
    const float* b_fc2    = (const float*)d_in[18];
    float* outp = (float*)d_out;

    char* ws = (char*)d_ws;
    size_t off = 0;
    auto take = [&](size_t bytes) -> char* {
        char* pp = ws + off;
        off = (off + bytes + 255) & ~(size_t)255;
        return pp;
    };
    int*   csr    = (int*)take((size_t)BB * ET * 4);
    int*   rowptr = (int*)take((size_t)BB * RP * 4);
    float* dinv   = (float*)take((size_t)NBt * 4);
    float* asrc   = (float*)take((size_t)NBt * 4);
    float* adst   = (float*)take((size_t)NBt * 4);
    float* pscal  = (float*)take((size_t)NBt * 4);
    float* gvec   = (float*)take((size_t)NBt * 4);
    f16*   bufA   = (f16*)take((size_t)NBt * CC * 2);       // f16 node features
    f16*   bufB   = (f16*)take((size_t)NBt * CC * 2);       // f16 node features
    float* P      = (float*)take((size_t)PROJ_ROWS * CC * 4); // table projections
    f16*   BWh    = (f16*)take((size_t)KSP * 8 * 64 * 8 * 2);
    f16*   BWl    = (f16*)take((size_t)KSP * 8 * 64 * 8 * 2);
    f16*   BGh    = (f16*)take((size_t)3 * 4 * 8 * 64 * 8 * 2);
    f16*   BGl    = (f16*)take((size_t)3 * 4 * 8 * 64 * 8 * 2);
    float* wsv    = (float*)take((size_t)3 * CC * 4);
    float* wdv    = (float*)take((size_t)3 * CC * 4);

    // merged CSR build + weight prep: blocks [0,BB) build, [BB, BB+21) prep
    const int prep_blocks = (NPREP + 1023) / 1024;
    k_build_prep<<<BB + prep_blocks, 1024, 0, stream>>>(
        edges, rowptr, csr, dinv,
        W_in, gat_W, gat_asrc, gat_adst, BWh, BWl, BGh, BGl, wsv, wdv);

    k_proj<<<596, 256, 0, stream>>>(poi, cat, lat, lon, BWh, BWl, P);
    k_assemble<<<NBt * 16 / 256, 256, 0, stream>>>(feature, P, bufB);
    k_agg<2><<<NBt / 8, 256, 0, stream>>>(bufB, dinv, nullptr, rowptr, csr, b_in,
                                          bufA, nullptr, nullptr);

    for (int i = 0; i < 3; ++i) {
        const f16* bh = BGh + (size_t)i * 4 * 8 * 64 * 8;
        const f16* bl = BGl + (size_t)i * 4 * 8 * 64 * 8;
        const float* ws_i = wsv + (size_t)i * CC;
        const float* wd_i = wdv + (size_t)i * CC;
        const float* gb = gat_b + (size_t)i * CC;
        k_gat_gemm<<<NBt / 32, 256, 0, stream>>>(bufA, bh, bl, ws_i, wd_i, bufB, asrc, adst);
        k_agg<0><<<NBt / 8, 256, 0, stream>>>(bufB, asrc, adst, rowptr, csr, gb,
                                              bufA, nullptr, nullptr);
        k_gat_gemm<<<NBt / 32, 256, 0, stream>>>(bufA, bh, bl, ws_i, wd_i, bufB, asrc, adst);
        if (i < 2) {
            k_agg<1><<<NBt / 8, 256, 0, stream>>>(bufB, asrc, adst, rowptr, csr, gb,
                                                  bufA, nullptr, nullptr);
        } else {
            // last agg: fuse the W_out per-node dot, write pscal only
            k_agg<3><<<NBt / 8, 256, 0, stream>>>(bufB, asrc, adst, rowptr, csr, gb,
                                                  bufA, W_out, pscal);
        }
    }

    k_out_agg<<<NBt / 4, 256, 0, stream>>>(pscal, dinv, rowptr, csr, b_out, gvec);
    k_fc<<<BB, 128, 0, stream>>>(gvec, W_fc1, b_fc1, W_fc2, b_fc2, outp);
}

// Round 17
// 273.625 us; speedup vs baseline: 1.1725x; 1.0603x over previous
//
#include <hip/hip_runtime.h>

// UserGraphNet: B=64 graphs, n=714 nodes, E=16384 edges (+n self loops), C=128.
// Round 16: quarter-wave aggregation — 4 nodes/wave (16-lane quarter per node):
// phase 1 register softmax with 4-shuffle quarter reductions; phase 2 gathers a
// full 256B row per quarter per step (4-edge unroll), accumulators fully
// lane-local (zero cross-lane shuffles). k_out_agg same treatment. Rest as
// round 15: split structure, f16 features, 2-term MFMA GEMMs, merged
// build+prep, table-projection embed, fused W_out dot, XCD swizzle.

#define BB 64
#define NN 714
#define EE 16384
#define ET (EE + NN)          // 17098 edges incl self loops
#define NBt (BB * NN)         // 45696 total nodes
#define CC 128
#define RP (NN + 1)           // rowptr entries per graph
#define DFAST 64              // max degree on the quarter-wave fast path (deg~24)
#define KSP 28                // total padded k-steps across 4 table projections
#define PROJ_ROWS 19021       // 5099 + 400 + 7128 + 6394

typedef _Float16 f16;
typedef __attribute__((ext_vector_type(8))) _Float16 f16x8;
typedef __attribute__((ext_vector_type(4))) _Float16 f16x4;
typedef __attribute__((ext_vector_type(4))) float f32x4;

__device__ __forceinline__ float lrelu01(float x) { return x > 0.f ? x : 0.01f * x; }
__device__ __forceinline__ float lrelu2(float x)  { return x > 0.f ? x : 0.2f  * x; }

__device__ __forceinline__ float wsum(float x) {
#pragma unroll
    for (int o = 32; o > 0; o >>= 1) x += __shfl_xor(x, o);
    return x;
}
// 16-lane (quarter-wave) reductions: xor offsets <=8 stay within the quarter
__device__ __forceinline__ float qsum(float x) {
#pragma unroll
    for (int o = 8; o > 0; o >>= 1) x += __shfl_xor(x, o);
    return x;
}
__device__ __forceinline__ float qmax(float x) {
#pragma unroll
    for (int o = 8; o > 0; o >>= 1) x = fmaxf(x, __shfl_xor(x, o));
    return x;
}

// Bijective XCD swizzle (m204)
__device__ __forceinline__ int xcd_swz(int bid, int nwg) {
    int q = nwg >> 3, r = nwg & 7;
    int x = bid & 7, l = bid >> 3;
    int base = (x < r) ? x * (q + 1) : r * (q + 1) + (x - r) * q;
    return base + l;
}

// ---- merged CSR build (blocks 0..BB-1) + weight prep (blocks BB..) ----
#define NSEG (KSP * 8 * 64)
#define NGAT (3 * 4 * 8 * 64)
#define NPREP (NSEG + NGAT + 3 * CC)
__global__ __launch_bounds__(1024) void k_build_prep(
    const int* __restrict__ edges, int* __restrict__ rowptr,
    int* __restrict__ csr_row, float* __restrict__ dinv,
    const float* __restrict__ W, const float* __restrict__ gat_W,
    const float* __restrict__ a_s, const float* __restrict__ a_d,
    f16* __restrict__ BWh, f16* __restrict__ BWl,
    f16* __restrict__ BGh, f16* __restrict__ BGl,
    float* __restrict__ wsv, float* __restrict__ wdv) {
    __shared__ int degs[NN];
    __shared__ int scan[1024];
    __shared__ int curs[NN];
    int t = threadIdx.x;
    if (blockIdx.x < BB) {
        // ---------------- CSR build ----------------
        int b = blockIdx.x;
        if (t < NN) degs[t] = 0;
        __syncthreads();
        int rr[17], cc[17];
#pragma unroll
        for (int q = 0; q < 17; ++q) {
            int e = q * 1024 + t;
            int r = -1, c = -1;
            if (e < ET) {
                if (e < EE) { r = edges[b * 2 * EE + e]; c = edges[b * 2 * EE + EE + e]; }
                else        { r = c = e - EE; }
                atomicAdd(&degs[c], 1);
            }
            rr[q] = r; cc[q] = c;
        }
        __syncthreads();
        int cnt = (t < NN) ? degs[t] : 0;
        scan[t] = cnt;
        __syncthreads();
        for (int off = 1; off < 1024; off <<= 1) {
            int val = (t >= off) ? scan[t - off] : 0;
            __syncthreads();
            scan[t] += val;
            __syncthreads();
        }
        if (t < NN) {
            rowptr[b * RP + t + 1] = scan[t];
            curs[t] = scan[t] - cnt;                   // exclusive prefix
            dinv[b * NN + t] = cnt > 0 ? rsqrtf((float)cnt) : 0.f;
        }
        if (t == 0) rowptr[b * RP] = 0;
        __syncthreads();
#pragma unroll
        for (int q = 0; q < 17; ++q) {
            if (cc[q] >= 0) {
                int slot = atomicAdd(&curs[cc[q]], 1); // LDS atomic
                csr_row[b * ET + slot] = rr[q];
            }
        }
        return;
    }
    // ---------------- weight prep ----------------
    int idx = (blockIdx.x - BB) * 1024 + t;
    if (idx < NSEG) {
        int lane = idx & 63, tc = idx >> 6;
        int ct = tc & 7, ks = tc >> 3;
        int tt = ks < 10 ? 0 : ks < 14 ? 1 : ks < 21 ? 2 : 3;
        int k0 = tt == 0 ? 0 : tt == 1 ? 10 : tt == 2 ? 14 : 21;
        const int Ktab[4] = {300, 100, 200, 200};
        const int Koff[4] = {0, 300, 400, 600};
        int ksl = ks - k0;
        f16x8 ph, pl;
#pragma unroll
        for (int j = 0; j < 8; ++j) {
            int k = ksl * 32 + (lane >> 4) * 8 + j;
            int c = ct * 16 + (lane & 15);
            float v = (k < Ktab[tt]) ? W[(size_t)(Koff[tt] + k) * CC + c] : 0.f;
            f16 hi = (f16)v;
            ph[j] = hi; pl[j] = (f16)(v - (float)hi);
        }
        *(f16x8*)(BWh + (size_t)idx * 8) = ph;
        *(f16x8*)(BWl + (size_t)idx * 8) = pl;
    } else if (idx < NSEG + NGAT) {
        int i2 = idx - NSEG;
        int lane = i2 & 63, tc = i2 >> 6;
        int ct = tc & 7; tc >>= 3;
        int ks = tc & 3, li = tc >> 2;
        const float* Wl = gat_W + (size_t)li * CC * CC;
        f16x8 ph, pl;
#pragma unroll
        for (int j = 0; j < 8; ++j) {
            int k = ks * 32 + (lane >> 4) * 8 + j;
            int c = ct * 16 + (lane & 15);
            float v = Wl[k * CC + c];
            f16 hi = (f16)v;
            ph[j] = hi; pl[j] = (f16)(v - (float)hi);
        }
        *(f16x8*)(BGh + (size_t)i2 * 8) = ph;
        *(f16x8*)(BGl + (size_t)i2 * 8) = pl;
    } else if (idx < NPREP) {
        int i2 = idx - NSEG - NGAT;
        int i = i2 >> 7, k = i2 & 127;
        const float* Wl = gat_W + (size_t)i * CC * CC;
        float s = 0.f, d = 0.f;
#pragma unroll 4
        for (int c = 0; c < CC; ++c) {
            float w = Wl[k * CC + c];
            s = fmaf(w, a_s[i * CC + c], s);
            d = fmaf(w, a_d[i * CC + c], d);
        }
        wsv[i * CC + k] = s; wdv[i * CC + k] = d;
    }
}

// ---- table-projection GEMM: P[t] = table[t] @ W_in[Koff:Koff+K]  (f32 out) ----
__global__ __launch_bounds__(256) void k_proj(
    const float* __restrict__ poi, const float* __restrict__ cat,
    const float* __restrict__ lat, const float* __restrict__ lon,
    const f16* __restrict__ Bh, const f16* __restrict__ Bl,
    float* __restrict__ P) {
    int bid = blockIdx.x;
    int t, r0;
    if (bid < 160)      { t = 0; r0 = bid * 32; }
    else if (bid < 173) { t = 1; r0 = (bid - 160) * 32; }
    else if (bid < 396) { t = 2; r0 = (bid - 173) * 32; }
    else                { t = 3; r0 = (bid - 396) * 32; }
    const int Ktab[4] = {300, 100, 200, 200};
    const int Rtab[4] = {5099, 400, 7128, 6394};
    const int Rofs[4] = {0, 5099, 5499, 12627};
    const int Kst[4]  = {10, 4, 7, 7};
    const int Bks0[4] = {0, 10, 14, 21};
    const float* tab = t == 0 ? poi : t == 1 ? cat : t == 2 ? lat : lon;
    int K = Ktab[t], R = Rtab[t], nks = Kst[t], bks = Bks0[t];
    int lane = threadIdx.x & 63, w = threadIdx.x >> 6;
    int ct0 = w * 2;
    f32x4 acc[2][2];
#pragma unroll
    for (int rt = 0; rt < 2; ++rt)
#pragma unroll
        for (int c = 0; c < 2; ++c) acc[rt][c] = (f32x4){0.f, 0.f, 0.f, 0.f};

    for (int ks = 0; ks < nks; ++ks) {
        int kbase = ks * 32 + (lane >> 4) * 8;
        f16x8 ah[2], al[2];
#pragma unroll
        for (int rt = 0; rt < 2; ++rt) {
            int row = r0 + rt * 16 + (lane & 15);
            int rowc = row < R ? row : R - 1;
            const float* rp = tab + (size_t)rowc * K;
            float v[8];
            if (kbase + 8 <= K) {
                float4 x0 = ((const float4*)(rp + kbase))[0];
                float4 x1 = ((const float4*)(rp + kbase))[1];
                v[0] = x0.x; v[1] = x0.y; v[2] = x0.z; v[3] = x0.w;
                v[4] = x1.x; v[5] = x1.y; v[6] = x1.z; v[7] = x1.w;
            } else if (kbase >= K) {
#pragma unroll
                for (int m = 0; m < 8; ++m) v[m] = 0.f;
            } else {
#pragma unroll
                for (int m = 0; m < 8; ++m) v[m] = (kbase + m < K) ? rp[kbase + m] : 0.f;
            }
#pragma unroll
            for (int j = 0; j < 8; ++j) {
                f16 hi = (f16)v[j];
                ah[rt][j] = hi; al[rt][j] = (f16)(v[j] - (float)hi);
            }
        }
#pragma unroll
        for (int cti = 0; cti < 2; ++cti) {
            int ct = ct0 + cti;
            f16x8 bh = *(const f16x8*)(Bh + ((size_t)((bks + ks) * 8 + ct) * 64 + lane) * 8);
            f16x8 bl = *(const f16x8*)(Bl + ((size_t)((bks + ks) * 8 + ct) * 64 + lane) * 8);
#pragma unroll
            for (int rt = 0; rt < 2; ++rt) {
                acc[rt][cti] = __builtin_amdgcn_mfma_f32_16x16x32_f16(ah[rt], bh, acc[rt][cti], 0, 0, 0);
                acc[rt][cti] = __builtin_amdgcn_mfma_f32_16x16x32_f16(al[rt], bh, acc[rt][cti], 0, 0, 0);
                acc[rt][cti] = __builtin_amdgcn_mfma_f32_16x16x32_f16(ah[rt], bl, acc[rt][cti], 0, 0, 0);
            }
        }
    }
#pragma unroll
    for (int rt = 0; rt < 2; ++rt)
#pragma unroll
        for (int cti = 0; cti < 2; ++cti)
#pragma unroll
            for (int i = 0; i < 4; ++i) {
                int row = r0 + rt * 16 + (lane >> 4) * 4 + i;
                if (row < R) {
                    int col = (ct0 + cti) * 16 + (lane & 15);
                    P[(size_t)(Rofs[t] + row) * CC + col] = acc[rt][cti][i];
                }
            }
}

// ---- per-node assembly: bufB[g] = P_poi[f0] + P_cat[f1] + P_lat[f3] + P_lon[f4] ----
__global__ __launch_bounds__(256) void k_assemble(
    const int* __restrict__ feature, const float* __restrict__ P,
    f16* __restrict__ out) {
    int tid = xcd_swz(blockIdx.x, gridDim.x) * 256 + threadIdx.x;
    int g = tid >> 4, c8 = (tid & 15) * 8;
    const int* f = feature + (size_t)g * 5;
    const float4* p0 = (const float4*)(P + (size_t)f[0] * CC + c8);
    const float4* p1 = (const float4*)(P + (size_t)(5099 + f[1]) * CC + c8);
    const float4* p2 = (const float4*)(P + (size_t)(5499 + f[3]) * CC + c8);
    const float4* p3 = (const float4*)(P + (size_t)(12627 + f[4]) * CC + c8);
    float4 a0 = p0[0], a1 = p0[1];
    float4 b0 = p1[0], b1 = p1[1];
    float4 c0 = p2[0], c1 = p2[1];
    float4 d0 = p3[0], d1 = p3[1];
    f16x8 r;
    r[0] = (f16)(a0.x + b0.x + c0.x + d0.x);
    r[1] = (f16)(a0.y + b0.y + c0.y + d0.y);
    r[2] = (f16)(a0.z + b0.z + c0.z + d0.z);
    r[3] = (f16)(a0.w + b0.w + c0.w + d0.w);
    r[4] = (f16)(a1.x + b1.x + c1.x + d1.x);
    r[5] = (f16)(a1.y + b1.y + c1.y + d1.y);
    r[6] = (f16)(a1.z + b1.z + c1.z + d1.z);
    r[7] = (f16)(a1.w + b1.w + c1.w + d1.w);
    *(f16x8*)(out + (size_t)g * CC + c8) = r;
}

// ---- GAT gemm, 32-row tile; f16 input (exact A, 2-term MFMA); f16 Hp out ----
__global__ __launch_bounds__(256) void k_gat_gemm(
    const f16* __restrict__ hin, const f16* __restrict__ Bh, const f16* __restrict__ Bl,
    const float* __restrict__ wsv, const float* __restrict__ wdv,
    f16* __restrict__ Hp, float* __restrict__ asrc, float* __restrict__ adst) {
    __shared__ __align__(16) f16 Ah[32 * 128];
    __shared__ float reds[256], redd[256];
    int t = threadIdx.x;
    int g0 = xcd_swz(blockIdx.x, gridDim.x) * 32;
    int lane = t & 63, w = t >> 6;
    int sr = t >> 3, skb = (t & 7) * 16;
    const f16x8* hrow = (const f16x8*)(hin + (size_t)(g0 + sr) * CC + skb);
    f16x8 hv0 = hrow[0], hv1 = hrow[1];
    float ps = 0.f, pd = 0.f;
#pragma unroll
    for (int m = 0; m < 8; ++m) {
        ps = fmaf((float)hv0[m], wsv[skb + m], ps);
        pd = fmaf((float)hv0[m], wdv[skb + m], pd);
        ps = fmaf((float)hv1[m], wsv[skb + 8 + m], ps);
        pd = fmaf((float)hv1[m], wdv[skb + 8 + m], pd);
    }
    {
        int kg0 = (t & 7) * 2;
        int ad0 = sr * 128 + ((kg0 ^ (sr & 7)) << 3);
        int ad1 = sr * 128 + (((kg0 + 1) ^ (sr & 7)) << 3);
        *(f16x8*)&Ah[ad0] = hv0;
        *(f16x8*)&Ah[ad1] = hv1;
    }
    reds[t] = ps; redd[t] = pd;
    __syncthreads();
    if (t < 32) {
        float s = 0.f, d = 0.f;
#pragma unroll
        for (int q = 0; q < 8; ++q) { s += reds[t * 8 + q]; d += redd[t * 8 + q]; }
        asrc[g0 + t] = s; adst[g0 + t] = d;
    }
    f32x4 acc[2][2];
#pragma unroll
    for (int rt = 0; rt < 2; ++rt)
#pragma unroll
        for (int c = 0; c < 2; ++c) acc[rt][c] = (f32x4){0.f, 0.f, 0.f, 0.f};
    int ct0 = w * 2;
#pragma unroll
    for (int ks = 0; ks < 4; ++ks) {
        f16x8 ahf[2];
#pragma unroll
        for (int rt = 0; rt < 2; ++rt) {
            int r = rt * 16 + (lane & 15);
            int kg = (lane >> 4) + ks * 4;
            int ad = r * 128 + ((kg ^ (r & 7)) << 3);
            ahf[rt] = *(const f16x8*)&Ah[ad];
        }
#pragma unroll
        for (int cti = 0; cti < 2; ++cti) {
            int ct = ct0 + cti;
            f16x8 bh = *(const f16x8*)(Bh + ((size_t)(ks * 8 + ct) * 64 + lane) * 8);
            f16x8 bl = *(const f16x8*)(Bl + ((size_t)(ks * 8 + ct) * 64 + lane) * 8);
#pragma unroll
            for (int rt = 0; rt < 2; ++rt) {
                acc[rt][cti] = __builtin_amdgcn_mfma_f32_16x16x32_f16(ahf[rt], bh, acc[rt][cti], 0, 0, 0);
                acc[rt][cti] = __builtin_amdgcn_mfma_f32_16x16x32_f16(ahf[rt], bl, acc[rt][cti], 0, 0, 0);
            }
        }
    }
#pragma unroll
    for (int rt = 0; rt < 2; ++rt)
#pragma unroll
        for (int cti = 0; cti < 2; ++cti)
#pragma unroll
            for (int i = 0; i < 4; ++i) {
                int row = g0 + rt * 16 + (lane >> 4) * 4 + i;
                int col = (ct0 + cti) * 16 + (lane & 15);
                Hp[(size_t)row * CC + col] = (f16)acc[rt][cti][i];
            }
}

// ---- unified aggregate kernel: 4 nodes per wave (16-lane quarter per node) ----
// MODE 0: GAT, out = lrelu01(t)+t. MODE 1: GAT, out = lrelu01(t).
// MODE 2: GCN, out = lrelu01(t). MODE 3: GAT plain, write only pscal = out.Wout.
template <int MODE>
__global__ __launch_bounds__(256) void k_agg(
    const f16* __restrict__ Hp, const float* __restrict__ aux,
    const float* __restrict__ adst, const int* __restrict__ rowptr,
    const int* __restrict__ csr_row, const float* __restrict__ bias,
    f16* __restrict__ out, const float* __restrict__ Wout, float* __restrict__ pscal) {
    __shared__ float2 pr[4][4][DFAST + 2];   // +2 pad: quarters land in distinct banks
    int wid = threadIdx.x >> 6, lane = threadIdx.x & 63;
    int quarter = lane >> 4, ql = lane & 15;
    int g = xcd_swz(blockIdx.x, gridDim.x) * 16 + wid * 4 + quarter;
    int b = g / NN, v = g - b * NN;
    int bN = b * NN, bE = b * ET;
    int s0 = rowptr[b * RP + v], s1 = rowptr[b * RP + v + 1];
    int deg = s1 - s0;

    if (deg <= DFAST) {
        int degp = (deg + 3) & ~3;                 // pad to multiple of 4
        float inv = 1.f;
        // ---- phase 1: <=4 edges/lane in registers, quarter reductions ----
        int rv[4];
        float wv[4];
        if (MODE == 2) {
            float dv = aux[g];
#pragma unroll
            for (int u = 0; u < 4; ++u) {
                int jj = ql + u * 16;
                rv[u] = 0; wv[u] = 0.f;
                if (jj < deg) { rv[u] = csr_row[bE + s0 + jj]; wv[u] = aux[bN + rv[u]] * dv; }
            }
        } else {
            float adv = adst[g];
            float ev[4];
#pragma unroll
            for (int u = 0; u < 4; ++u) {
                int jj = ql + u * 16;
                rv[u] = 0; ev[u] = -3.0e38f;
                if (jj < deg) { rv[u] = csr_row[bE + s0 + jj]; ev[u] = lrelu2(aux[bN + rv[u]] + adv); }
            }
            float m = qmax(fmaxf(fmaxf(ev[0], ev[1]), fmaxf(ev[2], ev[3])));
            float ss = 0.f;
#pragma unroll
            for (int u = 0; u < 4; ++u) {
                wv[u] = __expf(ev[u] - m);          // pads: exp(-inf)=0
                ss += wv[u];
            }
            ss = qsum(ss);
            inv = 1.f / (ss + 1e-16f);              // applied once at the end
        }
#pragma unroll
        for (int u = 0; u < 4; ++u) {
            int jj = ql + u * 16;
            if (jj < degp) pr[wid][quarter][jj] = make_float2(wv[u], __int_as_float(rv[u]));
        }
        // DS pipe is in-order per wave: phase-2 reads see this wave's writes.
        // ---- phase 2: full-row gather per quarter; 4 edges in flight; no shuffles ----
        const f16* Hb = Hp + (size_t)bN * CC;
        float acc0[8], acc1[8], acc2[8], acc3[8];
#pragma unroll
        for (int j = 0; j < 8; ++j) { acc0[j] = 0.f; acc1[j] = 0.f; acc2[j] = 0.f; acc3[j] = 0.f; }
        for (int jj = 0; jj < degp; jj += 4) {
            float2 p0 = pr[wid][quarter][jj];
            float2 p1 = pr[wid][quarter][jj + 1];
            float2 p2 = pr[wid][quarter][jj + 2];
            float2 p3 = pr[wid][quarter][jj + 3];
            f16x8 h0 = *(const f16x8*)(Hb + (size_t)__float_as_int(p0.y) * CC + ql * 8);
            f16x8 h1 = *(const f16x8*)(Hb + (size_t)__float_as_int(p1.y) * CC + ql * 8);
            f16x8 h2 = *(const f16x8*)(Hb + (size_t)__float_as_int(p2.y) * CC + ql * 8);
            f16x8 h3 = *(const f16x8*)(Hb + (size_t)__float_as_int(p3.y) * CC + ql * 8);
#pragma unroll
            for (int j = 0; j < 8; ++j) {
                acc0[j] = fmaf((float)h0[j], p0.x, acc0[j]);
                acc1[j] = fmaf((float)h1[j], p1.x, acc1[j]);
                acc2[j] = fmaf((float)h2[j], p2.x, acc2[j]);
                acc3[j] = fmaf((float)h3[j], p3.x, acc3[j]);
            }
        }
        // ---- epilogue: all 16 lanes live, accumulators lane-local ----
        float sc = (MODE == 2) ? 1.f : inv;
        float4 bb0 = ((const float4*)bias)[ql * 2];
        float4 bb1 = ((const float4*)bias)[ql * 2 + 1];
        float tv[8], ov[8];
#pragma unroll
        for (int j = 0; j < 8; ++j) {
            float x = acc0[j] + acc1[j] + acc2[j] + acc3[j];
            float bv = (j < 4) ? ((const float*)&bb0)[j] : ((const float*)&bb1)[j - 4];
            tv[j] = x * sc + bv;
            float l = lrelu01(tv[j]);
            ov[j] = (MODE == 0) ? l + tv[j] : l;
        }
        if (MODE == 3) {
            // fused out_dot: pscal[g] = ov . Wout
            float4 w0v = ((const float4*)Wout)[ql * 2];
            float4 w1v = ((const float4*)Wout)[ql * 2 + 1];
            float p = ov[0] * w0v.x + ov[1] * w0v.y + ov[2] * w0v.z + ov[3] * w0v.w
                    + ov[4] * w1v.x + ov[5] * w1v.y + ov[6] * w1v.z + ov[7] * w1v.w;
            p = qsum(p);
            if (ql == 0) pscal[g] = p;
        } else {
            f16x8 r;
#pragma unroll
            for (int j = 0; j < 8; ++j) r[j] = (f16)ov[j];
            *(f16x8*)(out + (size_t)g * CC + ql * 8) = r;
        }
        return;
    }
    // ---- fallback deg > DFAST: quarter-wave serial loop; ~never taken ----
    {
        float wsc0 = 0.f;
        float m = 0.f, inv = 1.f, adv = 0.f;
        if (MODE != 2) {
            adv = adst[g];
            m = -3.0e38f;
            for (int j = s0 + ql; j < s1; j += 16)
                m = fmaxf(m, lrelu2(aux[bN + csr_row[bE + j]] + adv));
            m = qmax(m);
            float ssum = 0.f;
            for (int j = s0 + ql; j < s1; j += 16)
                ssum += __expf(lrelu2(aux[bN + csr_row[bE + j]] + adv) - m);
            ssum = qsum(ssum);
            inv = 1.f / (ssum + 1e-16f);
        } else {
            wsc0 = aux[g];
        }
        float acc[8];
#pragma unroll
        for (int j = 0; j < 8; ++j) acc[j] = 0.f;
        for (int j = s0; j < s1; ++j) {
            int r = csr_row[bE + j];
            float wj = (MODE == 2) ? aux[bN + r]
                                   : __expf(lrelu2(aux[bN + r] + adv) - m) * inv;
            f16x8 h = *(const f16x8*)(Hp + (size_t)(bN + r) * CC + ql * 8);
#pragma unroll
            for (int k = 0; k < 8; ++k) acc[k] = fmaf(wj, (float)h[k], acc[k]);
        }
        if (MODE == 2) {
#pragma unroll
            for (int k = 0; k < 8; ++k) acc[k] *= wsc0;
        }
        float4 bb0 = ((const float4*)bias)[ql * 2];
        float4 bb1 = ((const float4*)bias)[ql * 2 + 1];
        float ov[8];
#pragma unroll
        for (int j = 0; j < 8; ++j) {
            float bv = (j < 4) ? ((const float*)&bb0)[j] : ((const float*)&bb1)[j - 4];
            float tvj = acc[j] + bv;
            float l = lrelu01(tvj);
            ov[j] = (MODE == 0) ? l + tvj : l;
        }
        if (MODE == 3) {
            float4 w0v = ((const float4*)Wout)[ql * 2];
            float4 w1v = ((const float4*)Wout)[ql * 2 + 1];
            float p = ov[0] * w0v.x + ov[1] * w0v.y + ov[2] * w0v.z + ov[3] * w0v.w
                    + ov[4] * w1v.x + ov[5] * w1v.y + ov[6] * w1v.z + ov[7] * w1v.w;
            p = qsum(p);
            if (ql == 0) pscal[g] = p;
        } else {
            f16x8 r;
#pragma unroll
            for (int j = 0; j < 8; ++j) r[j] = (f16)ov[j];
            *(f16x8*)(out + (size_t)g * CC + ql * 8) = r;
        }
    }
}

// ---- GCN2 aggregate over scalars: 4 nodes/wave, 16 lanes per node ----
__global__ __launch_bounds__(256) void k_out_agg(
    const float* __restrict__ p, const float* __restrict__ dinv,
    const int* __restrict__ rowptr, const int* __restrict__ csr_row,
    const float* __restrict__ bout, float* __restrict__ gv) {
    int wid = threadIdx.x >> 6, lane = threadIdx.x & 63;
    int quarter = lane >> 4, ql = lane & 15;
    int g = xcd_swz(blockIdx.x, gridDim.x) * 16 + wid * 4 + quarter;
    int b = g / NN, v = g - b * NN;
    int s0 = rowptr[b * RP + v], s1 = rowptr[b * RP + v + 1];
    float acc = 0.f;
    for (int j = s0 + ql; j < s1; j += 16) {
        int r = csr_row[b * ET + j];
        acc += dinv[b * NN + r] * p[b * NN + r];
    }
    acc = qsum(acc);
    if (ql == 0) gv[g] = lrelu01(acc * dinv[g] + bout[0]);
}

__global__ __launch_bounds__(128) void k_fc(
    const float* __restrict__ gv, const float* __restrict__ W1,
    const float* __restrict__ b1, const float* __restrict__ W2,
    const float* __restrict__ b2, float* __restrict__ outp) {
    __shared__ float gs[NN];
    __shared__ float s1[CC];
    int b = blockIdx.x, tx = threadIdx.x;
    for (int v = tx; v < NN; v += 128) gs[v] = gv[b * NN + v];
    __syncthreads();
    float acc = 0.f;
    for (int v = 0; v < NN; ++v) acc = fmaf(gs[v], W1[v * CC + tx], acc);
    float t = lrelu01(acc + b1[tx]);
    s1[tx] = t;
    __syncthreads();
    float acc2 = 0.f;
#pragma unroll
    for (int k = 0; k < CC; ++k) acc2 = fmaf(s1[k], W2[k * CC + tx], acc2);
    outp[b * CC + tx] = acc2 + b2[tx];
}

extern "C" void kernel_launch(void* const* d_in, const int* in_sizes, int n_in,
                              void* d_out, int out_size, void* d_ws, size_t ws_size,
                              hipStream_t stream) {
    const int*   feature  = (const int*)d_in[0];
    const int*   edges    = (const int*)d_in[1];
    const float* poi      = (const float*)d_in[3];
    const float* cat      = (const float*)d_in[4];
    const float* lat      = (const float*)d_in[5];
    const float* lon      = (const float*)d_in[6];
    const float* W_in     = (const float*)d_in[7];
    const float* b_in     = (const float*)d_in[8];
    const float* gat_W    = (const float*)d_in[9];
    const float* gat_asrc = (const float*)d_in[10];
    const float* gat_adst = (const float*)d_in[11];
    const float* gat_b    = (const float*)d_in[12];
    const float* W_out    = (const float*)d_in[13];
    const float* b_out    = (const float*)d_in[14];
    const float* W_fc1    = (const float*)d_in[15];
    const float* b_fc1    = (const float*)d_in[16];
    const float* W_fc2    = (const float*)d_in[17];
    const float* b_fc2    = (const float*)d_in[18];
    float* outp = (float*)d_out;

    char* ws = (char*)d_ws;
    size_t off = 0;
    auto take = [&](size_t bytes) -> char* {
        char* pp = ws + off;
        off = (off + bytes + 255) & ~(size_t)255;
        return pp;
    };
    int*   csr    = (int*)take((size_t)BB * ET * 4);
    int*   rowptr = (int*)take((size_t)BB * RP * 4);
    float* dinv   = (float*)take((size_t)NBt * 4);
    float* asrc   = (float*)take((size_t)NBt * 4);
    float* adst   = (float*)take((size_t)NBt * 4);
    float* pscal  = (float*)take((size_t)NBt * 4);
    float* gvec   = (float*)take((size_t)NBt * 4);
    f16*   bufA   = (f16*)take((size_t)NBt * CC * 2);       // f16 node features
    f16*   bufB   = (f16*)take((size_t)NBt * CC * 2);       // f16 node features
    float* P      = (float*)take((size_t)PROJ_ROWS * CC * 4); // table projections
    f16*   BWh    = (f16*)take((size_t)KSP * 8 * 64 * 8 * 2);
    f16*   BWl    = (f16*)take((size_t)KSP * 8 * 64 * 8 * 2);
    f16*   BGh    = (f16*)take((size_t)3 * 4 * 8 * 64 * 8 * 2);
    f16*   BGl    = (f16*)take((size_t)3 * 4 * 8 * 64 * 8 * 2);
    float* wsv    = (float*)take((size_t)3 * CC * 4);
    float* wdv    = (float*)take((size_t)3 * CC * 4);

    // merged CSR build + weight prep: blocks [0,BB) build, [BB, BB+21) prep
    const int prep_blocks = (NPREP + 1023) / 1024;
    k_build_prep<<<BB + prep_blocks, 1024, 0, stream>>>(
        edges, rowptr, csr, dinv,
        W_in, gat_W, gat_asrc, gat_adst, BWh, BWl, BGh, BGl, wsv, wdv);

    k_proj<<<596, 256, 0, stream>>>(poi, cat, lat, lon, BWh, BWl, P);
    k_assemble<<<NBt * 16 / 256, 256, 0, stream>>>(feature, P, bufB);
    k_agg<2><<<NBt / 16, 256, 0, stream>>>(bufB, dinv, nullptr, rowptr, csr, b_in,
                                           bufA, nullptr, nullptr);

    for (int i = 0; i < 3; ++i) {
        const f16* bh = BGh + (size_t)i * 4 * 8 * 64 * 8;
        const f16* bl = BGl + (size_t)i * 4 * 8 * 64 * 8;
        const float* ws_i = wsv + (size_t)i * CC;
        const float* wd_i = wdv + (size_t)i * CC;
        const float* gb = gat_b + (size_t)i * CC;
        k_gat_gemm<<<NBt / 32, 256, 0, stream>>>(bufA, bh, bl, ws_i, wd_i, bufB, asrc, adst);
        k_agg<0><<<NBt / 16, 256, 0, stream>>>(bufB, asrc, adst, rowptr, csr, gb,
                                               bufA, nullptr, nullptr);
        k_gat_gemm<<<NBt / 32, 256, 0, stream>>>(bufA, bh, bl, ws_i, wd_i, bufB, asrc, adst);
        if (i < 2) {
            k_agg<1><<<NBt / 16, 256, 0, stream>>>(bufB, asrc, adst, rowptr, csr, gb,
                                                   bufA, nullptr, nullptr);
        } else {
            // last agg: fuse the W_out per-node dot, write pscal only
            k_agg<3><<<NBt / 16, 256, 0, stream>>>(bufB, asrc, adst, rowptr, csr, gb,
                                                   bufA, W_out, pscal);
        }
    }

    k_out_agg<<<NBt / 16, 256, 0, stream>>>(pscal, dinv, rowptr, csr, b_out, gvec);
    k_fc<<<BB, 128, 0, stream>>>(gvec, W_fc1, b_fc1, W_fc2, b_fc2, outp);
}